// Round 13
// baseline (246.597 us; speedup 1.0000x reference)
//
#include <hip/hip_runtime.h>
#include <cstddef>

// ---------------------------------------------------------------------------
// Reins layer on MI355X — round 23 (= round 22 resubmitted; container flake,
// audit clean: polar loop barrier-free, uniform barriers, wave-locality holds
// at 512 threads, indices in range).
// R21 (8-wave sm_v) kept — best 245.8.  R22/R23 single change: inv_fft2_res
// at 512 threads (8 waves).  Polar prologue strides by 512 (per-thread serial
// work halves); FFT stages split by half-block (h=tid>>8 owns arrays 2h,2h+1;
// t=tid&255, index math unchanged); epilogue writes 2 arrays/half.  LDS
// 33.8 KB -> 4 blocks x 8 waves = 32 waves/CU (was 16).  Per-output numerics
// identical.  All other kernels byte-identical.
// ---------------------------------------------------------------------------

using bf16x8 = __attribute__((ext_vector_type(8))) short;   // 8 bf16 in 4 VGPRs
using f32x4  = __attribute__((ext_vector_type(4))) float;

__device__ inline short f2bf(float f) {
  union { float f; unsigned u; } v; v.f = f;
  unsigned r = v.u + 0x7FFFu + ((v.u >> 16) & 1u);  // round-to-nearest-even
  return (short)(r >> 16);
}
__device__ inline float bf2f(short s) {
  union { unsigned u; float f; } v; v.u = ((unsigned)(unsigned short)s) << 16;
  return v.f;
}
__device__ inline void async16(const void* g, void* l) {
  __builtin_amdgcn_global_load_lds(
      (const __attribute__((address_space(1))) void*)g,
      (__attribute__((address_space(3))) void*)l, 16, 0, 0);
}
__device__ inline float fast_atan2(float y, float x) {   // max err ~1.5e-4 rad
  float ax = fabsf(x), ay = fabsf(y);
  float mx = fmaxf(ax, ay), mn = fminf(ax, ay);
  float a = mn * __frcp_rn(mx);
  float s = a * a;
  float r = fmaf(fmaf(fmaf(-0.0464964749f, s, 0.15931422f), s, -0.327622764f),
                 s * a, a);
  if (ay > ax) r = 1.5707963267948966f - r;
  if (x < 0.f) r = 3.14159265358979f - r;
  return (y < 0.f) ? -r : r;
}

__device__ inline int PADi(int i) { return i + (i >> 5); }   // LDS anti-conflict
__device__ inline int rev4_8(int t) {                         // reverse 4 base-4 digits
  return ((t & 3) << 6) | (((t >> 2) & 3) << 4) | (((t >> 4) & 3) << 2) | ((t >> 6) & 3);
}

// ---- radix-2 DIF FFT8, natural-order in & out ------------------------------
__device__ inline void fft8_fwd(float* xr, float* xi) {      // X[k]=Σx e^{-2πikb/8}
  const float r = 0.70710678118654752f;
  float ar[4], ai[4], br[4], bi[4], tr, ti;
  ar[0]=xr[0]+xr[4]; ai[0]=xi[0]+xi[4]; br[0]=xr[0]-xr[4]; bi[0]=xi[0]-xi[4];
  ar[1]=xr[1]+xr[5]; ai[1]=xi[1]+xi[5];
  tr=xr[1]-xr[5]; ti=xi[1]-xi[5]; br[1]=(tr+ti)*r; bi[1]=(ti-tr)*r;   // *(1-i)r
  ar[2]=xr[2]+xr[6]; ai[2]=xi[2]+xi[6];
  tr=xr[2]-xr[6]; ti=xi[2]-xi[6]; br[2]=ti; bi[2]=-tr;                // *(-i)
  ar[3]=xr[3]+xr[7]; ai[3]=xi[3]+xi[7];
  tr=xr[3]-xr[7]; ti=xi[3]-xi[7]; br[3]=(ti-tr)*r; bi[3]=-(tr+ti)*r;  // *-(1+i)r
  float u0r=ar[0]+ar[2], u0i=ai[0]+ai[2], u1r=ar[1]+ar[3], u1i=ai[1]+ai[3];
  float v0r=ar[0]-ar[2], v0i=ai[0]-ai[2];
  tr=ar[1]-ar[3]; ti=ai[1]-ai[3];
  float v1r=ti, v1i=-tr;                                              // *(-i)
  xr[0]=u0r+u1r; xi[0]=u0i+u1i; xr[4]=u0r-u1r; xi[4]=u0i-u1i;
  xr[2]=v0r+v1r; xi[2]=v0i+v1i; xr[6]=v0r-v1r; xi[6]=v0i-v1i;
  u0r=br[0]+br[2]; u0i=bi[0]+bi[2]; u1r=br[1]+br[3]; u1i=bi[1]+bi[3];
  v0r=br[0]-br[2]; v0i=bi[0]-bi[2];
  tr=br[1]-br[3]; ti=bi[1]-bi[3];
  v1r=ti; v1i=-tr;
  xr[1]=u0r+u1r; xi[1]=u0i+u1i; xr[5]=u0r-u1r; xi[5]=u0i-u1i;
  xr[3]=v0r+v1r; xi[3]=v0i+v1i; xr[7]=v0r-v1r; xi[7]=v0i-v1i;
}
__device__ inline void fft8_inv(float* xr, float* xi) {      // X[k]=Σx e^{+2πikb/8}
  const float r = 0.70710678118654752f;
  float ar[4], ai[4], br[4], bi[4], tr, ti;
  ar[0]=xr[0]+xr[4]; ai[0]=xi[0]+xi[4]; br[0]=xr[0]-xr[4]; bi[0]=xi[0]-xi[4];
  ar[1]=xr[1]+xr[5]; ai[1]=xi[1]+xi[5];
  tr=xr[1]-xr[5]; ti=xi[1]-xi[5]; br[1]=(tr-ti)*r; bi[1]=(tr+ti)*r;   // *(1+i)r
  ar[2]=xr[2]+xr[6]; ai[2]=xi[2]+xi[6];
  tr=xr[2]-xr[6]; ti=xi[2]-xi[6]; br[2]=-ti; bi[2]=tr;                // *(+i)
  ar[3]=xr[3]+xr[7]; ai[3]=xi[3]+xi[7];
  tr=xr[3]-xr[7]; ti=xi[3]-xi[7]; br[3]=-(tr+ti)*r; bi[3]=(tr-ti)*r;  // *(-1+i)r
  float u0r=ar[0]+ar[2], u0i=ai[0]+ai[2], u1r=ar[1]+ar[3], u1i=ai[1]+ai[3];
  float v0r=ar[0]-ar[2], v0i=ai[0]-ai[2];
  tr=ar[1]-ar[3]; ti=ai[1]-ai[3];
  float v1r=-ti, v1i=tr;                                              // *(+i)
  xr[0]=u0r+u1r; xi[0]=u0i+u1i; xr[4]=u0r-u1r; xi[4]=u0i-u1i;
  xr[2]=v0r+v1r; xi[2]=v0i+v1i; xr[6]=v0r-v1r; xi[6]=v0i-v1i;
  u0r=br[0]+br[2]; u0i=bi[0]+bi[2]; u1r=br[1]+br[3]; u1i=bi[1]+bi[3];
  v0r=br[0]-br[2]; v0i=bi[0]-bi[2];
  tr=br[1]-br[3]; ti=bi[1]-bi[3];
  v1r=-ti; v1i=tr;
  xr[1]=u0r+u1r; xi[1]=u0i+u1i; xr[5]=u0r-u1r; xi[5]=u0i-u1i;
  xr[3]=v0r+v1r; xi[3]=v0i+v1i; xr[7]=v0r-v1r; xi[7]=v0i-v1i;
}

// 1024-pt in-place radix-4 DIF, NP interleaved FFTs sharing barriers.
// Stage 0 mixes cross-wave -> block barrier.  Stages 1..4 are wave-local
// (wave w touches only elements 256w..256w+255) -> wave_barrier only.
// Final block barrier before cross-wave epilogue readers.
template <int SIGN, int NP>
__device__ inline void fft1024xN(float2 (*zb)[1056], int t) {
#pragma unroll
  for (int s = 0; s < 5; ++s) {
    const int Q = 256 >> (2 * s);
    const int j = t & (Q - 1);
    const int i0 = ((t & ~(Q - 1)) << 2) + j;
    const float ang = (float)SIGN * 6.283185307179586f * (float)j / (float)(4 * Q);
    float s1, c1; __sincosf(ang, &s1, &c1);
    const float c2 = c1 * c1 - s1 * s1, s2 = 2.f * c1 * s1;
    const float c3 = c2 * c1 - s2 * s1, s3 = c2 * s1 + s2 * c1;
#pragma unroll
    for (int p = 0; p < NP; ++p) {
      float2* z = zb[p];
      float2 x0 = z[PADi(i0)];
      float2 x1 = z[PADi(i0 + Q)];
      float2 x2 = z[PADi(i0 + 2 * Q)];
      float2 x3 = z[PADi(i0 + 3 * Q)];
      float t0x = x0.x + x2.x, t0y = x0.y + x2.y;
      float t1x = x0.x - x2.x, t1y = x0.y - x2.y;
      float t2x = x1.x + x3.x, t2y = x1.y + x3.y;
      float t3x = x1.x - x3.x, t3y = x1.y - x3.y;
      float u0x = t0x + t2x, u0y = t0y + t2y;
      float u2x = t0x - t2x, u2y = t0y - t2y;
      float u1x, u1y, u3x, u3y;
      if (SIGN < 0) { u1x = t1x + t3y; u1y = t1y - t3x; u3x = t1x - t3y; u3y = t1y + t3x; }
      else          { u1x = t1x - t3y; u1y = t1y + t3x; u3x = t1x + t3y; u3y = t1y - t3x; }
      z[PADi(i0)]         = make_float2(u0x, u0y);
      z[PADi(i0 + Q)]     = make_float2(u1x * c1 - u1y * s1, u1x * s1 + u1y * c1);
      z[PADi(i0 + 2 * Q)] = make_float2(u2x * c2 - u2y * s2, u2x * s2 + u2y * c2);
      z[PADi(i0 + 3 * Q)] = make_float2(u3x * c3 - u3y * s3, u3x * s3 + u3y * c3);
    }
    if (s == 0 || s == 4) __syncthreads();          // cross-wave boundaries only
    else                  __builtin_amdgcn_wave_barrier();  // compile-time order pin
  }
}

// 512-thread variant for inv: half-block h owns arrays pbase=2h..2h+1.
// Same per-array index math (t in [0,256)); stage 0 sync covers all 512
// (both halves at same stage); stages 1..3 wave-local; final sync after s4.
template <int SIGN>
__device__ inline void fft1024_pair512(float2 (*zb)[1056], int t, int pbase) {
#pragma unroll
  for (int s = 0; s < 5; ++s) {
    const int Q = 256 >> (2 * s);
    const int j = t & (Q - 1);
    const int i0 = ((t & ~(Q - 1)) << 2) + j;
    const float ang = (float)SIGN * 6.283185307179586f * (float)j / (float)(4 * Q);
    float s1, c1; __sincosf(ang, &s1, &c1);
    const float c2 = c1 * c1 - s1 * s1, s2 = 2.f * c1 * s1;
    const float c3 = c2 * c1 - s2 * s1, s3 = c2 * s1 + s2 * c1;
#pragma unroll
    for (int p2 = 0; p2 < 2; ++p2) {
      float2* z = zb[pbase + p2];
      float2 x0 = z[PADi(i0)];
      float2 x1 = z[PADi(i0 + Q)];
      float2 x2 = z[PADi(i0 + 2 * Q)];
      float2 x3 = z[PADi(i0 + 3 * Q)];
      float t0x = x0.x + x2.x, t0y = x0.y + x2.y;
      float t1x = x0.x - x2.x, t1y = x0.y - x2.y;
      float t2x = x1.x + x3.x, t2y = x1.y + x3.y;
      float t3x = x1.x - x3.x, t3y = x1.y - x3.y;
      float u0x = t0x + t2x, u0y = t0y + t2y;
      float u2x = t0x - t2x, u2y = t0y - t2y;
      float u1x, u1y, u3x, u3y;
      if (SIGN < 0) { u1x = t1x + t3y; u1y = t1y - t3x; u3x = t1x - t3y; u3y = t1y + t3x; }
      else          { u1x = t1x - t3y; u1y = t1y + t3x; u3x = t1x + t3y; u3y = t1y - t3x; }
      z[PADi(i0)]         = make_float2(u0x, u0y);
      z[PADi(i0 + Q)]     = make_float2(u1x * c1 - u1y * s1, u1x * s1 + u1y * c1);
      z[PADi(i0 + 2 * Q)] = make_float2(u2x * c2 - u2y * s2, u2x * s2 + u2y * c2);
      z[PADi(i0 + 3 * Q)] = make_float2(u3x * c3 - u3y * s3, u3x * s3 + u3y * c3);
    }
    if (s == 0 || s == 4) __syncthreads();          // all 512, both halves in lockstep stage
    else                  __builtin_amdgcn_wave_barrier();
  }
}

// ---- 1. fused fwd fft2 + amp/phase + conv work as extra blocks -------------
__global__ __launch_bounds__(256) void fwd_fft2_amp_conv(
    const float* __restrict__ feats,
    short* __restrict__ ampb, short* __restrict__ phaseb,
    const float* __restrict__ w1, const float* __restrict__ w2,
    const float* __restrict__ w3, const float* __restrict__ w4,
    const float* __restrict__ lt1, const float* __restrict__ lt2,
    const int* __restrict__ layerp,
    short* __restrict__ Wdst, short* __restrict__ Tdst,
    float* __restrict__ out) {
  if (blockIdx.x >= 1024) {                         // ---- conv part ----
    const int id = blockIdx.x - 1024;
    const int t4 = threadIdx.x * 4;
    if (id < 4096) {                                // weights: 4 x 1024 rows
      const int z = id >> 10, row = id & 1023;
      const float* W = (z == 0 ? w1 : z == 1 ? w2 : z == 2 ? w3 : w4)
                       + (size_t)row * 1024;
      short* D = Wdst + ((size_t)z * 1024 + row) * 1024;
      float4 v = *(const float4*)(W + t4);
      D[t4] = f2bf(v.x); D[t4 + 1] = f2bf(v.y); D[t4 + 2] = f2bf(v.z); D[t4 + 3] = f2bf(v.w);
    } else if (id < 4608) {                         // tokens: 4 x 128 rows
      const int i2 = id - 4096;
      const int zz = i2 >> 7, row = i2 & 127;
      const int z = zz & 1, shift = zz >> 1;
      short* D = Tdst + ((size_t)zz * 128 + row) * 1024;
      if (row + shift < 100) {
        const float* S = (z ? lt2 : lt1) + (size_t)layerp[0] * 102400
                         + (size_t)(row + shift) * 1024;
        float4 v = *(const float4*)(S + t4);
        D[t4] = f2bf(v.x); D[t4 + 1] = f2bf(v.y); D[t4 + 2] = f2bf(v.z); D[t4 + 3] = f2bf(v.w);
      } else {
        D[t4] = 0; D[t4 + 1] = 0; D[t4 + 2] = 0; D[t4 + 3] = 0;
      }
    } else {                                        // cls: 32 blocks x 256
      const int i = (id - 4608) * 256 + threadIdx.x;
      out[i] = feats[i];
    }
    return;
  }
  // ---- FFT part ----
  __shared__ float2 zb[4][1056];                    // 33.8 KB
  const int t = threadIdx.x;
  const int n = blockIdx.x;
  const float* base = feats + 8192 + (size_t)n * 8192;
#pragma unroll
  for (int p = 0; p < 4; ++p) {
    const float* x0 = base + (size_t)(2 * p) * 1024;
    const float* x1 = x0 + 1024;
#pragma unroll
    for (int m = 0; m < 4; ++m) {
      const int c = t + 256 * m;
      zb[p][PADi(c)] = make_float2(x0[c], x1[c]);
    }
  }
  __syncthreads();
  fft1024xN<-1, 4>(zb, t);
  const int rt = rev4_8(t);
  short* ab = ampb + (size_t)n * 8192;
  short* pb = phaseb + (size_t)n * 8192;
#pragma unroll
  for (int m = 0; m < 4; ++m) {
    const int k = 256 * m + t;
    const int kk = (1024 - k) & 1023;
    const int pos  = 4 * rt + m;
    const int pos2 = 4 * rev4_8(kk & 255) + (kk >> 8);
    float xr[8], xi[8];
#pragma unroll
    for (int p = 0; p < 4; ++p) {
      float2 Z = zb[p][PADi(pos)];
      float2 W = zb[p][PADi(pos2)];
      xr[2 * p]     = 0.5f * (Z.x + W.x);
      xi[2 * p]     = 0.5f * (Z.y - W.y);
      xr[2 * p + 1] = 0.5f * (Z.y + W.y);
      xi[2 * p + 1] = 0.5f * (W.x - Z.x);
    }
    fft8_fwd(xr, xi);                               // X[kb] along batch dim
#pragma unroll
    for (int kb = 0; kb < 8; ++kb) {
      float sr = xr[kb], si = xi[kb];
      float r2 = sr * sr + si * si;
      if (r2 < 1e-5f) r2 = 1e-5f;                   // _replace_denormals(re^2+im^2)
      float a = sqrtf(r2);
      float rr = (sr < 1e-5f && sr > -1e-5f) ? 1e-5f : sr;
      float ph = fast_atan2(si, rr);
      ab[kb * 1024 + k] = f2bf(a);
      pb[kb * 1024 + k] = f2bf(ph);
    }
  }
}

// ---- 2. GEMM1+softmax (x<128, 64x128 tile) and v-GEMM (x>=128), one grid ---
// 512 threads (8 waves).  Softmax part: per-wave 32x32 sub-tile; staging by
// tid<256 only; softmax 8 lanes/row.  v-GEMM: per-wave 64x32, 2 async16/thr.
__global__ __launch_bounds__(512) void gemm_sm_v(
    const short* A0, const short* A1,       // 8192 x 1024 bf16 (phase, amp)
    const short* Tok,                       // 4 x 128 x 1024 bf16 tokens
    const short* Wall,                      // 4 x 1024 x 1024 bf16 weights
    const float* bt1, const float* bt2,     // b_t2f, b_t2f2
    short* __restrict__ awb,                // 2 x 8192 x 128 bf16
    short* __restrict__ vrow) {             // 2 x 128 x 1024 bf16
  __shared__ __align__(16) char smem[37120];
  const int z = blockIdx.z;
  const int tid = threadIdx.x;
  const int wave = tid >> 6, lane = tid & 63;
  const int m16 = lane & 15, quad = lane >> 4;
  const int fcol = ((quad ^ ((m16 >> 1) & 3)) * 8) + m16 * 32;

  if (blockIdx.x >= 128) {                          // ---- v-GEMM part (BK=32) --
    const int jbBlk = blockIdx.x - 128;             // column block 0..7
    const short* A = Tok + (size_t)(2 + z) * 128 * 1024;   // shifted tokens
    const short* B = Wall + (size_t)z * 1024 * 1024;       // w_t2f / w_t2f2
    const float* bias = z ? bt2 : bt1;
    short* C = vrow + (size_t)z * 128 * 1024;
    const int K = 1024;
    short* As = (short*)smem;                       // 128 x 32
    short* Bs = (short*)(smem + 8192);              // 128 x 32
    const int wm = (wave & 1) * 64, wn = (wave >> 1) * 32;
    f32x4 acc[4][2];
#pragma unroll
    for (int i = 0; i < 4; ++i)
#pragma unroll
      for (int j = 0; j < 2; ++j) acc[i][j] = (f32x4){0.f, 0.f, 0.f, 0.f};
    const int r0v = tid >> 2;                       // 0..127
    const int cswv = (((tid & 3) ^ ((r0v >> 1) & 3)) * 8);
    const short* aSrc = A + (size_t)r0v * K + cswv;
    const short* bSrc = B + (size_t)(jbBlk * 128 + r0v) * K + cswv;
    short* aDst = As + tid * 8;
    short* bDst = Bs + tid * 8;
    for (int k0 = 0; k0 < K; k0 += 32) {
      async16(aSrc + k0, aDst);
      async16(bSrc + k0, bDst);
      __syncthreads();
      bf16x8 af[4], bg[2];
#pragma unroll
      for (int ib = 0; ib < 4; ++ib)
        af[ib] = *(const bf16x8*)(As + (wm + ib * 16) * 32 + fcol);
#pragma unroll
      for (int jb2 = 0; jb2 < 2; ++jb2)
        bg[jb2] = *(const bf16x8*)(Bs + (wn + jb2 * 16) * 32 + fcol);
#pragma unroll
      for (int ib = 0; ib < 4; ++ib)
#pragma unroll
        for (int jb2 = 0; jb2 < 2; ++jb2)
          acc[ib][jb2] = __builtin_amdgcn_mfma_f32_16x16x32_bf16(af[ib], bg[jb2], acc[ib][jb2], 0, 0, 0);
      __syncthreads();
    }
#pragma unroll
    for (int ib = 0; ib < 4; ++ib) {
      const int rowb = wm + ib * 16 + quad * 4;
#pragma unroll
      for (int jb2 = 0; jb2 < 2; ++jb2) {
        const int col = jbBlk * 128 + wn + jb2 * 16 + m16;
        const float bcv = bias[col];
#pragma unroll
        for (int r = 0; r < 4; ++r)
          C[(size_t)(rowb + r) * 1024 + col] = f2bf(acc[ib][jb2][r] + bcv);
      }
    }
    return;
  }

  // ---- softmax-GEMM part, 64x128 tile, BK=64, 8 waves ----
  const short* A = z ? A1 : A0;
  const short* B = Tok + (size_t)z * 128 * 1024;
  const int K = 1024;
  short* As = (short*)smem;                         // [2][64*32]  (8 KB)   K-loop only
  short* Bs = (short*)(smem + 8192);                // [2][128*32] (16 KB)  K-loop only
  float (*ltile)[129] = (float(*)[129])(smem);      // 64x129 f32 (33 KB)  post-loop overlay
  float (*red1)[8] = (float(*)[8])(smem + 33024);   // 64x8 (2 KB)
  float (*red2)[8] = (float(*)[8])(smem + 35072);   // 64x8 (2 KB)
  const int wm = (wave & 1) * 32, wn = (wave >> 1) * 32;
  f32x4 acc[2][2];
#pragma unroll
  for (int i = 0; i < 2; ++i)
#pragma unroll
    for (int j = 0; j < 2; ++j) acc[i][j] = (f32x4){0.f, 0.f, 0.f, 0.f};
  // staging by tid<256 only — identical address pattern to R20
  const int r0s = (tid & 255) >> 2;
  const int csws = (((tid & 3) ^ ((r0s >> 1) & 3)) * 8);
  const short* aSrc  = A + (size_t)(blockIdx.x * 64 + r0s) * K + csws;
  const short* bSrc0 = B + (size_t)r0s * K + csws;
  const short* bSrc1 = bSrc0 + (size_t)64 * K;
  short* aDst0  = As + (tid & 255) * 8;             // sub0: 64x32
  short* aDst1  = As + 2048 + (tid & 255) * 8;      // sub1
  short* bDst00 = Bs + (tid & 255) * 8;             // sub0 rows 0-63
  short* bDst01 = Bs + 2048 + (tid & 255) * 8;      // sub0 rows 64-127
  short* bDst10 = Bs + 4096 + (tid & 255) * 8;      // sub1 rows 0-63
  short* bDst11 = Bs + 6144 + (tid & 255) * 8;      // sub1 rows 64-127
  for (int k0 = 0; k0 < K; k0 += 64) {
    if (tid < 256) {
      async16(aSrc + k0,       aDst0);
      async16(aSrc + k0 + 32,  aDst1);
      async16(bSrc0 + k0,      bDst00);
      async16(bSrc1 + k0,      bDst01);
      async16(bSrc0 + k0 + 32, bDst10);
      async16(bSrc1 + k0 + 32, bDst11);
    }
    __syncthreads();
#pragma unroll
    for (int sub = 0; sub < 2; ++sub) {
      bf16x8 af[2], bg[2];
#pragma unroll
      for (int ib = 0; ib < 2; ++ib)
        af[ib] = *(const bf16x8*)(As + sub * 2048 + (wm + ib * 16) * 32 + fcol);
#pragma unroll
      for (int jb = 0; jb < 2; ++jb)
        bg[jb] = *(const bf16x8*)(Bs + sub * 4096 + (wn + jb * 16) * 32 + fcol);
#pragma unroll
      for (int ib = 0; ib < 2; ++ib)
#pragma unroll
        for (int jb = 0; jb < 2; ++jb)
          acc[ib][jb] = __builtin_amdgcn_mfma_f32_16x16x32_bf16(af[ib], bg[jb], acc[ib][jb], 0, 0, 0);
    }
    __syncthreads();
  }
  // staging region dead; ltile overlays it (ordered by barrier above)
#pragma unroll
  for (int ib = 0; ib < 2; ++ib)
#pragma unroll
    for (int jb = 0; jb < 2; ++jb)
#pragma unroll
      for (int r = 0; r < 4; ++r)
        ltile[wm + ib * 16 + quad * 4 + r][wn + jb * 16 + m16] = acc[ib][jb][r];
  __syncthreads();
  const int row = tid >> 3, l8 = tid & 7;           // 8 lanes/row, 64 rows
  float s = 0.f, q = 0.f;
  for (int c = l8; c < 100; c += 8) { float x = ltile[row][c]; s += x; q += x * x; }
  red1[row][l8] = s; red2[row][l8] = q;
  __syncthreads();
  float ssum = 0.f, qsum = 0.f;
#pragma unroll
  for (int i = 0; i < 8; ++i) { ssum += red1[row][i]; qsum += red2[row][i]; }
  __syncthreads();
  const float mu = ssum * 0.01f;
  const float rinv = rsqrtf(fmaxf(qsum * 0.01f - mu * mu, 0.f) + 1e-5f);
  float mx = -3.4e38f;
  for (int c = l8; c < 100; c += 8) {
    float x = ltile[row][c];
    if (z == 1) x = (x - mu) * rinv;                // instance-norm (amp path)
    x *= 0.03125f;                                  // * C^{-1/2}
    ltile[row][c] = x;
    mx = fmaxf(mx, x);
  }
  red1[row][l8] = mx;
  __syncthreads();
#pragma unroll
  for (int i = 0; i < 8; ++i) mx = fmaxf(mx, red1[row][i]);
  __syncthreads();
  float es = 0.f;
  for (int c = l8; c < 100; c += 8) {
    float e = __expf(ltile[row][c] - mx);
    ltile[row][c] = e; es += e;
  }
  red1[row][l8] = es;
  __syncthreads();
  float tot = 0.f;
#pragma unroll
  for (int i = 0; i < 8; ++i) tot += red1[row][i];
  const float inv = 1.f / tot;
  short* Aout = awb + ((size_t)z * 8192 + (size_t)blockIdx.x * 64 + row) * 128;
  for (int c = l8; c < 100; c += 8)
    if (c >= 1) Aout[c - 1] = f2bf(ltile[row][c] * inv);  // aw[k]=attn[k+1]
  for (int k = l8; k < 128; k += 8)
    if (k >= 99) Aout[k] = 0;                             // zero pad 99..127
}

// ------------- 64x128-tile GEMM (V2T) ---------------------------------------
__global__ __launch_bounds__(256) void gemm64(
    const short* A0, const short* A1,       // M x K bf16
    const short* B0, const short* B1,       // 128 x K bf16
    void* C0v, void* C1v, int K, int ldc) {
  const int z = blockIdx.z;
  const short* A = z ? A1 : A0;
  const short* B = z ? B1 : B0;
  void* Cv = z ? C1v : C0v;
  __shared__ __align__(16) short As[64 * 32];
  __shared__ __align__(16) short Bs[128 * 32];
  const int tid = threadIdx.x;
  const int wave = tid >> 6, lane = tid & 63;
  const int m16 = lane & 15, quad = lane >> 4;
  const int wm = (wave & 1) * 32, wn = (wave >> 1) * 64;
  f32x4 acc[2][4];
#pragma unroll
  for (int i = 0; i < 2; ++i)
#pragma unroll
    for (int j = 0; j < 4; ++j) acc[i][j] = (f32x4){0.f, 0.f, 0.f, 0.f};
  const int r0 = tid >> 2;
  const int csw = (((tid & 3) ^ ((r0 >> 1) & 3)) * 8);
  const short* aSrc  = A + (size_t)(blockIdx.x * 64 + r0) * K + csw;
  const short* bSrc0 = B + (size_t)r0 * K + csw;
  const short* bSrc1 = bSrc0 + (size_t)64 * K;
  short* aDst  = As + tid * 8;
  short* bDst0 = Bs + tid * 8;
  short* bDst1 = Bs + 2048 + tid * 8;
  const int fcol = ((quad ^ ((m16 >> 1) & 3)) * 8) + m16 * 32;
  for (int k0 = 0; k0 < K; k0 += 32) {
    async16(aSrc + k0, aDst);
    async16(bSrc0 + k0, bDst0);
    async16(bSrc1 + k0, bDst1);
    __syncthreads();
    bf16x8 af[2], bg[4];
#pragma unroll
    for (int ib = 0; ib < 2; ++ib)
      af[ib] = *(const bf16x8*)(As + (wm + ib * 16) * 32 + fcol);
#pragma unroll
    for (int jb = 0; jb < 4; ++jb)
      bg[jb] = *(const bf16x8*)(Bs + (wn + jb * 16) * 32 + fcol);
#pragma unroll
    for (int ib = 0; ib < 2; ++ib)
#pragma unroll
      for (int jb = 0; jb < 4; ++jb)
        acc[ib][jb] = __builtin_amdgcn_mfma_f32_16x16x32_bf16(af[ib], bg[jb], acc[ib][jb], 0, 0, 0);
    __syncthreads();
  }
#pragma unroll
  for (int ib = 0; ib < 2; ++ib) {
    const int rowb = blockIdx.x * 64 + wm + ib * 16 + quad * 4;
#pragma unroll
    for (int jb = 0; jb < 4; ++jb) {
      const int col = wn + jb * 16 + m16;
#pragma unroll
      for (int r = 0; r < 4; ++r)
        ((short*)Cv)[(size_t)(rowb + r) * ldc + col] = f2bf(acc[ib][jb][r]);
    }
  }
}

// ---- dual-K fused GEMM, 256x256 tile, 8-phase schedule (T3+T4+T5) ----------
#define SLOT8(VM, DOSTAGE)                                                   \
  do {                                                                       \
    const short* Asl = &As[k & 3][0];                                        \
    const short* Bsl = &Bs[k & 3][0];                                        \
    const int kp = k + 3;                                                    \
    const short *as0 = nullptr, *as1 = nullptr, *bs0 = nullptr, *bs1 = nullptr; \
    short *ad = nullptr, *bd = nullptr;                                      \
    if (DOSTAGE) {                                                           \
      ad = &As[kp & 3][0]; bd = &Bs[kp & 3][0];                              \
      if (kp < NS1) {                                                        \
        const int c = kp << 5;                                               \
        as0 = A1 + aO1_0 + c; as1 = A1 + aO1_1 + c;                          \
        bs0 = B1 + bO1_0 + c; bs1 = B1 + bO1_1 + c;                          \
      } else {                                                               \
        const int c = (kp - NS1) << 5;                                       \
        as0 = A2 + aO2_0 + c; as1 = A2 + aO2_1 + c;                          \
        bs0 = B2 + bO2_0 + c; bs1 = B2 + bO2_1 + c;                          \
      }                                                                      \
    }                                                                        \
    bf16x8 bg[4], af[4];                                                     \
    /* ---- phase A: bg + af(rows wm..wm+63) + stage A-half of k+3 ---- */   \
    _Pragma("unroll")                                                        \
    for (int jb = 0; jb < 4; ++jb)                                           \
      bg[jb] = *(const bf16x8*)(Bsl + (wn + jb * 16) * 32 + fcol);           \
    _Pragma("unroll")                                                        \
    for (int ib = 0; ib < 4; ++ib)                                           \
      af[ib] = *(const bf16x8*)(Asl + (wm + ib * 16) * 32 + fcol);           \
    if (DOSTAGE) {                                                           \
      async16(as0, ad + tid * 8);                                            \
      async16(as1, ad + 4096 + tid * 8);                                     \
    }                                                                        \
    __builtin_amdgcn_sched_barrier(0);                                       \
    __builtin_amdgcn_s_barrier();                                            \
    asm volatile("s_waitcnt lgkmcnt(0)" ::: "memory");                       \
    __builtin_amdgcn_s_setprio(1);                                           \
    _Pragma("unroll")                                                        \
    for (int ib = 0; ib < 4; ++ib)                                           \
      _Pragma("unroll")                                                      \
      for (int jb = 0; jb < 4; ++jb)                                         \
        acc[ib][jb] = __builtin_amdgcn_mfma_f32_16x16x32_bf16(               \
            af[ib], bg[jb], acc[ib][jb], 0, 0, 0);                           \
    __builtin_amdgcn_s_setprio(0);                                           \
    __builtin_amdgcn_sched_barrier(0);                                       \
    __builtin_amdgcn_s_barrier();                                            \
    /* ---- phase B: af(rows wm+64..wm+127) + stage B-half of k+3 ---- */    \
    _Pragma("unroll")                                                        \
    for (int ib = 0; ib < 4; ++ib)                                           \
      af[ib] = *(const bf16x8*)(Asl + (wm + 64 + ib * 16) * 32 + fcol);      \
    if (DOSTAGE) {                                                           \
      async16(bs0, bd + tid * 8);                                            \
      async16(bs1, bd + 4096 + tid * 8);                                     \
    }                                                                        \
    __builtin_amdgcn_sched_barrier(0);                                       \
    __builtin_amdgcn_s_barrier();                                            \
    asm volatile("s_waitcnt lgkmcnt(0)" ::: "memory");                       \
    __builtin_amdgcn_s_setprio(1);                                           \
    _Pragma("unroll")                                                        \
    for (int ib = 0; ib < 4; ++ib)                                           \
      _Pragma("unroll")                                                      \
      for (int jb = 0; jb < 4; ++jb)                                         \
        acc[ib + 4][jb] = __builtin_amdgcn_mfma_f32_16x16x32_bf16(           \
            af[ib], bg[jb], acc[ib + 4][jb], 0, 0, 0);                       \
    __builtin_amdgcn_s_setprio(0);                                           \
    asm volatile("s_waitcnt vmcnt(" #VM ")" ::: "memory");                   \
    __builtin_amdgcn_sched_barrier(0);                                       \
    __builtin_amdgcn_s_barrier();                                            \
  } while (0)

__global__ __launch_bounds__(512) void gemm256_dual(
    const short* A1_0, const short* A1_1,   // M x K1
    const short* B1_0, const short* B1_1,   // N x K1
    const short* A2_0, const short* A2_1,   // M x K2
    const short* B2_0, const short* B2_1,   // N x K2
    const float* bias0, const float* bias1,
    short* C0, short* C1, int K1, int K2, int ldc) {
  const int z = blockIdx.z;
  const short* A1 = z ? A1_1 : A1_0;
  const short* B1 = z ? B1_1 : B1_0;
  const short* A2 = z ? A2_1 : A2_0;
  const short* B2 = z ? B2_1 : B2_0;
  const float* bias = z ? bias1 : bias0;
  short* C = z ? C1 : C0;
  __shared__ __align__(16) short As[4][8192];       // 4 slots x 256x32 (64 KB)
  __shared__ __align__(16) short Bs[4][8192];       // 4 slots x 256x32 (64 KB)
  const int tid = threadIdx.x;
  const int wave = tid >> 6, lane = tid & 63;
  const int m16 = lane & 15, quad = lane >> 4;
  const int wm = (wave & 1) * 128, wn = (wave >> 1) * 64;
  const int fcol = ((quad ^ ((m16 >> 1) & 3)) * 8) + m16 * 32;
  const int r0 = tid >> 2;                          // 0..127
  const int csw = (((tid & 3) ^ ((r0 >> 1) & 3)) * 8);
  const size_t aO1_0 = (size_t)(blockIdx.x * 256 + r0) * (size_t)K1 + csw;
  const size_t aO1_1 = aO1_0 + (size_t)128 * K1;
  const size_t bO1_0 = (size_t)(blockIdx.y * 256 + r0) * (size_t)K1 + csw;
  const size_t bO1_1 = bO1_0 + (size_t)128 * K1;
  const size_t aO2_0 = (size_t)(blockIdx.x * 256 + r0) * (size_t)K2 + csw;
  const size_t aO2_1 = aO2_0 + (size_t)128 * K2;
  const size_t bO2_0 = (size_t)(blockIdx.y * 256 + r0) * (size_t)K2 + csw;
  const size_t bO2_1 = bO2_0 + (size_t)128 * K2;
  const int NS1 = K1 >> 5;                          // 4
  const int NT  = NS1 + (K2 >> 5);                  // 36
  f32x4 acc[8][4];
#pragma unroll
  for (int i = 0; i < 8; ++i)
#pragma unroll
    for (int j = 0; j < 4; ++j) acc[i][j] = (f32x4){0.f, 0.f, 0.f, 0.f};
  // prologue: stage slots 0..2 fully (12 loads in flight per wave)
#pragma unroll
  for (int k = 0; k < 3; ++k) {
    short* ad = &As[k & 3][0];
    short* bd = &Bs[k & 3][0];
    const short *as0, *as1, *bs0, *bs1;
    if (k < NS1) {
      const int c = k << 5;
      as0 = A1 + aO1_0 + c; as1 = A1 + aO1_1 + c;
      bs0 = B1 + bO1_0 + c; bs1 = B1 + bO1_1 + c;
    } else {
      const int c = (k - NS1) << 5;
      as0 = A2 + aO2_0 + c; as1 = A2 + aO2_1 + c;
      bs0 = B2 + bO2_0 + c; bs1 = B2 + bO2_1 + c;
    }
    async16(as0, ad + tid * 8);
    async16(as1, ad + 4096 + tid * 8);
    async16(bs0, bd + tid * 8);
    async16(bs1, bd + 4096 + tid * 8);
  }
  // gate slot 0: oldest 4 of 12 loads must land
  asm volatile("s_waitcnt vmcnt(8)" ::: "memory");
  __builtin_amdgcn_sched_barrier(0);
  __builtin_amdgcn_s_barrier();
#pragma unroll 1
  for (int k = 0; k < NT - 3; ++k) {                // k = 0..32, always stages
    SLOT8(8, true);
  }
  { const int k = NT - 3; SLOT8(4, false); }        // gate slot NT-2
  { const int k = NT - 2; SLOT8(0, false); }        // gate slot NT-1
  { const int k = NT - 1; SLOT8(0, false); }        // last slot
  // epilogue
#pragma unroll
  for (int ib = 0; ib < 8; ++ib) {
    const int rowb = blockIdx.x * 256 + wm + ib * 16 + quad * 4;
#pragma unroll
    for (int jb = 0; jb < 4; ++jb) {
      const int col = blockIdx.y * 256 + wn + jb * 16 + m16;
      const float bcv = bias[col];
#pragma unroll
      for (int r = 0; r < 4; ++r) {
        const size_t idx = (size_t)(rowb + r) * (size_t)ldc + col;
        C[idx] = f2bf(acc[ib][jb][r] + bcv);
      }
    }
  }
}
#undef SLOT8

// ---- fused inverse: polar->z, FFT8 inv, Hermitian-packed ifft, residual ----
// R22/R23: 512 threads.  Polar strides by 512 (per-thread serial work halves);
// FFT stages: half-block h owns arrays 2h..2h+1 (fft1024_pair512); epilogue
// writes 2 arrays per half.  LDS 33.8 KB -> 4 blocks x 8 waves = 32 waves/CU.
__global__ __launch_bounds__(512) void inv_fft2_res(const short* __restrict__ dPb,
                                                    const short* __restrict__ dAb,
                                                    const float* __restrict__ feats,
                                                    const float* __restrict__ scalep,
                                                    float* __restrict__ out) {
  __shared__ float2 zb[4][1056];                    // 33.8 KB
  const int tid = threadIdx.x;
  const int h = tid >> 8;                           // half-block 0/1
  const int t = tid & 255;
  const int n = blockIdx.x;
  const short* pp = dPb + (size_t)n * 8192;
  const short* ap = dAb + (size_t)n * 8192;
  const float invs = 0.022097086912079608f;         // 1/sqrt(2048)
  const float inv8 = 0.35355339059327373f;          // 1/sqrt(8) (ortho)
  for (int k = tid; k < 513; k += 512) {            // all 512 threads; tid 0 also k=512
    float zr[8], zi[8];
#pragma unroll
    for (int b = 0; b < 8; ++b) {
      float p = bf2f(pp[b * 1024 + k]);
      float a = bf2f(ap[b * 1024 + k]) * invs;
      float s, c; __sincosf(p, &s, &c);
      zr[b] = c * a; zi[b] = s * a;
    }
    fft8_inv(zr, zi);                               // Z[bp] = ifft along batch
#pragma unroll
    for (int l = 0; l < 4; ++l) {
      const int bp = 2 * l;                         // pair (bp, bp+1)
      float ax = zr[bp] * inv8,     ay = zi[bp] * inv8;
      float bx = zr[bp + 1] * inv8, by = zi[bp + 1] * inv8;
      zb[l][PADi(k)] = make_float2(ax - by, ay + bx);   // Y = Za + i*Zb
      if (k >= 1 && k <= 511)
        zb[l][PADi(1024 - k)] = make_float2(ax + by, bx - ay);
    }
  }
  __syncthreads();
  fft1024_pair512<1>(zb, t, 2 * h);
  const int rt = rev4_8(t);
  const float s = scalep[0] * 0.03125f;             // scale * 1/sqrt(1024)
#pragma unroll
  for (int ll = 0; ll < 2; ++ll) {
    const int l = 2 * h + ll;
    const size_t ob0 = 8192 + ((size_t)n * 8 + 2 * l) * 1024;
    const size_t ob1 = ob0 + 1024;
#pragma unroll
    for (int m = 0; m < 4; ++m) {
      const int nn = 256 * m + t;
      float2 y = zb[l][PADi(4 * rt + m)];
      out[ob0 + nn] = feats[ob0 + nn] + y.x * s;
      out[ob1 + nn] = feats[ob1 + nn] + y.y * s;
    }
  }
}

// ---------------------------------------------------------------------------
extern "C" void kernel_launch(void* const* d_in, const int* in_sizes, int n_in,
                              void* d_out, int out_size, void* d_ws, size_t ws_size,
                              hipStream_t stream) {
  const float* feats  = (const float*)d_in[0];
  const float* lt1    = (const float*)d_in[1];
  const float* lt2    = (const float*)d_in[2];
  const float* w_t2f  = (const float*)d_in[3];
  const float* b_t2f  = (const float*)d_in[4];
  const float* w_df   = (const float*)d_in[5];
  const float* b_df   = (const float*)d_in[6];
  const float* w_t2f2 = (const float*)d_in[7];
  const float* b_t2f2 = (const float*)d_in[8];
  const float* w_df2  = (const float*)d_in[9];
  const float* b_df2  = (const float*)d_in[10];
  const float* scalep = (const float*)d_in[11];
  const int*   layerp = (const int*)d_in[12];
  float* out = (float*)d_out;
  (void)in_sizes; (void)n_in; (void)out_size; (void)ws_size;

  const size_t SZ = 8192ull * 1024ull;              // 8,388,608 elements
  short* Pa   = (short*)d_ws;                       // phase bf16 (16 MB)
  short* Pb   = Pa + SZ;                            // amp   bf16 (16 MB)
  short* awb  = Pb + SZ;                            // aw bf16, 2x8192x128 (4 MB)
  short* Tok  = awb + 2ull * 8192 * 128;            // tokens bf16, 4x128x1024 (1 MB)
  short* Wall = Tok + 4ull * 128 * 1024;            // weights bf16, 4x1024x1024 (8 MB)
  short* vrow = Wall + 4ull * 1024 * 1024;          // v row-major, 2x128x1024 (0.5 MB)
  short* V2T  = vrow + 2ull * 128 * 1024;           // w_df@v^T, 2x1024x128 (0.5 MB)
  short* dP   = V2T + 2ull * 1024 * 128;            // d_phase bf16 (16 MB)
  short* dA   = dP + SZ;                            // d_amp bf16 (16 MB)

  // 1: fwd fft2 + amp/phase (blocks 0..1023) + weight/token convert + cls copy
  fwd_fft2_amp_conv<<<dim3(5664), dim3(256), 0, stream>>>(
      feats, Pb, Pa, w_t2f, w_t2f2, w_df, w_df2, lt1, lt2, layerp,
      Wall, Tok, out);
  // 2: GEMM1+in+softmax (x<128, 64x128 tiles) and v-GEMM (x>=128), 512 thr
  gemm_sm_v<<<dim3(136, 1, 2), dim3(512), 0, stream>>>(
      Pa, Pb, Tok, Wall, b_t2f, b_t2f2, awb, vrow);
  // 3: V2T = w_df @ v^T  (M=1024, N=128, K=1024), bf16, ldc=128
  gemm64<<<dim3(16, 1, 2), dim3(256), 0, stream>>>(
      Wall + 2 * 1024 * 1024, Wall + 3 * 1024 * 1024,
      vrow, vrow + 128 * 1024,
      V2T, V2T + 1024 * 128, 1024, 128);
  // 4: d = aw @ V2T^T + P @ w_df^T + b_df  (M=8192, N=1024, K=128+1024), bf16
  gemm256_dual<<<dim3(32, 4, 2), dim3(512), 0, stream>>>(
      awb, awb + 8192 * 128, V2T, V2T + 1024 * 128,
      Pa, Pb, Wall + 2 * 1024 * 1024, Wall + 3 * 1024 * 1024,
      b_df, b_df2, dP, dA, 128, 1024, 1024);
  // 5: fused inverse: polar -> ifft8 -> ifft_c -> residual (1 block/n, 512 thr)
  inv_fft2_res<<<dim3(1024), dim3(512), 0, stream>>>(dP, dA, feats, scalep, out);
}

// Round 14
// 245.192 us; speedup vs baseline: 1.0057x; 1.0057x over previous
//
#include <hip/hip_runtime.h>
#include <cstddef>

// ---------------------------------------------------------------------------
// Reins layer on MI355X — round 24.
// R23 post-mortem: 512-thread inv = neutral (246.6 vs 245.8) -> revert inv to
// R21's 256-thread version (best-measured).  R24 single new change: gemm64
// (V2T) runs on only 32 of 256 CUs with a fully-synchronous K-loop (stage ->
// vmcnt(0)+barrier -> MFMA -> barrier, 32 iters of exposed HBM latency).
// Double-buffered with counted vmcnt (the R11-proven discipline): issue next
// buffer's 3 loads, s_waitcnt vmcnt(3) (never 0 in-loop), raw s_barrier +
// sched_barrier(0).  Buffer b is re-staged only after the barrier closing the
// compute that read b.  All other kernels byte-identical to R21.
// ---------------------------------------------------------------------------

using bf16x8 = __attribute__((ext_vector_type(8))) short;   // 8 bf16 in 4 VGPRs
using f32x4  = __attribute__((ext_vector_type(4))) float;

__device__ inline short f2bf(float f) {
  union { float f; unsigned u; } v; v.f = f;
  unsigned r = v.u + 0x7FFFu + ((v.u >> 16) & 1u);  // round-to-nearest-even
  return (short)(r >> 16);
}
__device__ inline float bf2f(short s) {
  union { unsigned u; float f; } v; v.u = ((unsigned)(unsigned short)s) << 16;
  return v.f;
}
__device__ inline void async16(const void* g, void* l) {
  __builtin_amdgcn_global_load_lds(
      (const __attribute__((address_space(1))) void*)g,
      (__attribute__((address_space(3))) void*)l, 16, 0, 0);
}
__device__ inline float fast_atan2(float y, float x) {   // max err ~1.5e-4 rad
  float ax = fabsf(x), ay = fabsf(y);
  float mx = fmaxf(ax, ay), mn = fminf(ax, ay);
  float a = mn * __frcp_rn(mx);
  float s = a * a;
  float r = fmaf(fmaf(fmaf(-0.0464964749f, s, 0.15931422f), s, -0.327622764f),
                 s * a, a);
  if (ay > ax) r = 1.5707963267948966f - r;
  if (x < 0.f) r = 3.14159265358979f - r;
  return (y < 0.f) ? -r : r;
}

__device__ inline int PADi(int i) { return i + (i >> 5); }   // LDS anti-conflict
__device__ inline int rev4_8(int t) {                         // reverse 4 base-4 digits
  return ((t & 3) << 6) | (((t >> 2) & 3) << 4) | (((t >> 4) & 3) << 2) | ((t >> 6) & 3);
}

// ---- radix-2 DIF FFT8, natural-order in & out ------------------------------
__device__ inline void fft8_fwd(float* xr, float* xi) {      // X[k]=Σx e^{-2πikb/8}
  const float r = 0.70710678118654752f;
  float ar[4], ai[4], br[4], bi[4], tr, ti;
  ar[0]=xr[0]+xr[4]; ai[0]=xi[0]+xi[4]; br[0]=xr[0]-xr[4]; bi[0]=xi[0]-xi[4];
  ar[1]=xr[1]+xr[5]; ai[1]=xi[1]+xi[5];
  tr=xr[1]-xr[5]; ti=xi[1]-xi[5]; br[1]=(tr+ti)*r; bi[1]=(ti-tr)*r;   // *(1-i)r
  ar[2]=xr[2]+xr[6]; ai[2]=xi[2]+xi[6];
  tr=xr[2]-xr[6]; ti=xi[2]-xi[6]; br[2]=ti; bi[2]=-tr;                // *(-i)
  ar[3]=xr[3]+xr[7]; ai[3]=xi[3]+xi[7];
  tr=xr[3]-xr[7]; ti=xi[3]-xi[7]; br[3]=(ti-tr)*r; bi[3]=-(tr+ti)*r;  // *-(1+i)r
  float u0r=ar[0]+ar[2], u0i=ai[0]+ai[2], u1r=ar[1]+ar[3], u1i=ai[1]+ai[3];
  float v0r=ar[0]-ar[2], v0i=ai[0]-ai[2];
  tr=ar[1]-ar[3]; ti=ai[1]-ai[3];
  float v1r=ti, v1i=-tr;                                              // *(-i)
  xr[0]=u0r+u1r; xi[0]=u0i+u1i; xr[4]=u0r-u1r; xi[4]=u0i-u1i;
  xr[2]=v0r+v1r; xi[2]=v0i+v1i; xr[6]=v0r-v1r; xi[6]=v0i-v1i;
  u0r=br[0]+br[2]; u0i=bi[0]+bi[2]; u1r=br[1]+br[3]; u1i=bi[1]+bi[3];
  v0r=br[0]-br[2]; v0i=bi[0]-bi[2];
  tr=br[1]-br[3]; ti=bi[1]-bi[3];
  v1r=ti; v1i=-tr;
  xr[1]=u0r+u1r; xi[1]=u0i+u1i; xr[5]=u0r-u1r; xi[5]=u0i-u1i;
  xr[3]=v0r+v1r; xi[3]=v0i+v1i; xr[7]=v0r-v1r; xi[7]=v0i-v1i;
}
__device__ inline void fft8_inv(float* xr, float* xi) {      // X[k]=Σx e^{+2πikb/8}
  const float r = 0.70710678118654752f;
  float ar[4], ai[4], br[4], bi[4], tr, ti;
  ar[0]=xr[0]+xr[4]; ai[0]=xi[0]+xi[4]; br[0]=xr[0]-xr[4]; bi[0]=xi[0]-xi[4];
  ar[1]=xr[1]+xr[5]; ai[1]=xi[1]+xi[5];
  tr=xr[1]-xr[5]; ti=xi[1]-xi[5]; br[1]=(tr-ti)*r; bi[1]=(tr+ti)*r;   // *(1+i)r
  ar[2]=xr[2]+xr[6]; ai[2]=xi[2]+xi[6];
  tr=xr[2]-xr[6]; ti=xi[2]-xi[6]; br[2]=-ti; bi[2]=tr;                // *(+i)
  ar[3]=xr[3]+xr[7]; ai[3]=xi[3]+xi[7];
  tr=xr[3]-xr[7]; ti=xi[3]-xi[7]; br[3]=-(tr+ti)*r; bi[3]=(tr-ti)*r;  // *(-1+i)r
  float u0r=ar[0]+ar[2], u0i=ai[0]+ai[2], u1r=ar[1]+ar[3], u1i=ai[1]+ai[3];
  float v0r=ar[0]-ar[2], v0i=ai[0]-ai[2];
  tr=ar[1]-ar[3]; ti=ai[1]-ai[3];
  float v1r=-ti, v1i=tr;                                              // *(+i)
  xr[0]=u0r+u1r; xi[0]=u0i+u1i; xr[4]=u0r-u1r; xi[4]=u0i-u1i;
  xr[2]=v0r+v1r; xi[2]=v0i+v1i; xr[6]=v0r-v1r; xi[6]=v0i-v1i;
  u0r=br[0]+br[2]; u0i=bi[0]+bi[2]; u1r=br[1]+br[3]; u1i=bi[1]+bi[3];
  v0r=br[0]-br[2]; v0i=bi[0]-bi[2];
  tr=br[1]-br[3]; ti=bi[1]-bi[3];
  v1r=-ti; v1i=tr;
  xr[1]=u0r+u1r; xi[1]=u0i+u1i; xr[5]=u0r-u1r; xi[5]=u0i-u1i;
  xr[3]=v0r+v1r; xi[3]=v0i+v1i; xr[7]=v0r-v1r; xi[7]=v0i-v1i;
}

// 1024-pt in-place radix-4 DIF, NP interleaved FFTs sharing barriers.
// Stage 0 mixes cross-wave -> block barrier.  Stages 1..4 are wave-local
// (wave w touches only elements 256w..256w+255) -> wave_barrier only.
// Final block barrier before cross-wave epilogue readers.
template <int SIGN, int NP>
__device__ inline void fft1024xN(float2 (*zb)[1056], int t) {
#pragma unroll
  for (int s = 0; s < 5; ++s) {
    const int Q = 256 >> (2 * s);
    const int j = t & (Q - 1);
    const int i0 = ((t & ~(Q - 1)) << 2) + j;
    const float ang = (float)SIGN * 6.283185307179586f * (float)j / (float)(4 * Q);
    float s1, c1; __sincosf(ang, &s1, &c1);
    const float c2 = c1 * c1 - s1 * s1, s2 = 2.f * c1 * s1;
    const float c3 = c2 * c1 - s2 * s1, s3 = c2 * s1 + s2 * c1;
#pragma unroll
    for (int p = 0; p < NP; ++p) {
      float2* z = zb[p];
      float2 x0 = z[PADi(i0)];
      float2 x1 = z[PADi(i0 + Q)];
      float2 x2 = z[PADi(i0 + 2 * Q)];
      float2 x3 = z[PADi(i0 + 3 * Q)];
      float t0x = x0.x + x2.x, t0y = x0.y + x2.y;
      float t1x = x0.x - x2.x, t1y = x0.y - x2.y;
      float t2x = x1.x + x3.x, t2y = x1.y + x3.y;
      float t3x = x1.x - x3.x, t3y = x1.y - x3.y;
      float u0x = t0x + t2x, u0y = t0y + t2y;
      float u2x = t0x - t2x, u2y = t0y - t2y;
      float u1x, u1y, u3x, u3y;
      if (SIGN < 0) { u1x = t1x + t3y; u1y = t1y - t3x; u3x = t1x - t3y; u3y = t1y + t3x; }
      else          { u1x = t1x - t3y; u1y = t1y + t3x; u3x = t1x + t3y; u3y = t1y - t3x; }
      z[PADi(i0)]         = make_float2(u0x, u0y);
      z[PADi(i0 + Q)]     = make_float2(u1x * c1 - u1y * s1, u1x * s1 + u1y * c1);
      z[PADi(i0 + 2 * Q)] = make_float2(u2x * c2 - u2y * s2, u2x * s2 + u2y * c2);
      z[PADi(i0 + 3 * Q)] = make_float2(u3x * c3 - u3y * s3, u3x * s3 + u3y * c3);
    }
    if (s == 0 || s == 4) __syncthreads();          // cross-wave boundaries only
    else                  __builtin_amdgcn_wave_barrier();  // compile-time order pin
  }
}

// ---- 1. fused fwd fft2 + amp/phase + conv work as extra blocks -------------
__global__ __launch_bounds__(256) void fwd_fft2_amp_conv(
    const float* __restrict__ feats,
    short* __restrict__ ampb, short* __restrict__ phaseb,
    const float* __restrict__ w1, const float* __restrict__ w2,
    const float* __restrict__ w3, const float* __restrict__ w4,
    const float* __restrict__ lt1, const float* __restrict__ lt2,
    const int* __restrict__ layerp,
    short* __restrict__ Wdst, short* __restrict__ Tdst,
    float* __restrict__ out) {
  if (blockIdx.x >= 1024) {                         // ---- conv part ----
    const int id = blockIdx.x - 1024;
    const int t4 = threadIdx.x * 4;
    if (id < 4096) {                                // weights: 4 x 1024 rows
      const int z = id >> 10, row = id & 1023;
      const float* W = (z == 0 ? w1 : z == 1 ? w2 : z == 2 ? w3 : w4)
                       + (size_t)row * 1024;
      short* D = Wdst + ((size_t)z * 1024 + row) * 1024;
      float4 v = *(const float4*)(W + t4);
      D[t4] = f2bf(v.x); D[t4 + 1] = f2bf(v.y); D[t4 + 2] = f2bf(v.z); D[t4 + 3] = f2bf(v.w);
    } else if (id < 4608) {                         // tokens: 4 x 128 rows
      const int i2 = id - 4096;
      const int zz = i2 >> 7, row = i2 & 127;
      const int z = zz & 1, shift = zz >> 1;
      short* D = Tdst + ((size_t)zz * 128 + row) * 1024;
      if (row + shift < 100) {
        const float* S = (z ? lt2 : lt1) + (size_t)layerp[0] * 102400
                         + (size_t)(row + shift) * 1024;
        float4 v = *(const float4*)(S + t4);
        D[t4] = f2bf(v.x); D[t4 + 1] = f2bf(v.y); D[t4 + 2] = f2bf(v.z); D[t4 + 3] = f2bf(v.w);
      } else {
        D[t4] = 0; D[t4 + 1] = 0; D[t4 + 2] = 0; D[t4 + 3] = 0;
      }
    } else {                                        // cls: 32 blocks x 256
      const int i = (id - 4608) * 256 + threadIdx.x;
      out[i] = feats[i];
    }
    return;
  }
  // ---- FFT part ----
  __shared__ float2 zb[4][1056];                    // 33.8 KB
  const int t = threadIdx.x;
  const int n = blockIdx.x;
  const float* base = feats + 8192 + (size_t)n * 8192;
#pragma unroll
  for (int p = 0; p < 4; ++p) {
    const float* x0 = base + (size_t)(2 * p) * 1024;
    const float* x1 = x0 + 1024;
#pragma unroll
    for (int m = 0; m < 4; ++m) {
      const int c = t + 256 * m;
      zb[p][PADi(c)] = make_float2(x0[c], x1[c]);
    }
  }
  __syncthreads();
  fft1024xN<-1, 4>(zb, t);
  const int rt = rev4_8(t);
  short* ab = ampb + (size_t)n * 8192;
  short* pb = phaseb + (size_t)n * 8192;
#pragma unroll
  for (int m = 0; m < 4; ++m) {
    const int k = 256 * m + t;
    const int kk = (1024 - k) & 1023;
    const int pos  = 4 * rt + m;
    const int pos2 = 4 * rev4_8(kk & 255) + (kk >> 8);
    float xr[8], xi[8];
#pragma unroll
    for (int p = 0; p < 4; ++p) {
      float2 Z = zb[p][PADi(pos)];
      float2 W = zb[p][PADi(pos2)];
      xr[2 * p]     = 0.5f * (Z.x + W.x);
      xi[2 * p]     = 0.5f * (Z.y - W.y);
      xr[2 * p + 1] = 0.5f * (Z.y + W.y);
      xi[2 * p + 1] = 0.5f * (W.x - Z.x);
    }
    fft8_fwd(xr, xi);                               // X[kb] along batch dim
#pragma unroll
    for (int kb = 0; kb < 8; ++kb) {
      float sr = xr[kb], si = xi[kb];
      float r2 = sr * sr + si * si;
      if (r2 < 1e-5f) r2 = 1e-5f;                   // _replace_denormals(re^2+im^2)
      float a = sqrtf(r2);
      float rr = (sr < 1e-5f && sr > -1e-5f) ? 1e-5f : sr;
      float ph = fast_atan2(si, rr);
      ab[kb * 1024 + k] = f2bf(a);
      pb[kb * 1024 + k] = f2bf(ph);
    }
  }
}

// ---- 2. GEMM1+softmax (x<128, 64x128 tile) and v-GEMM (x>=128), one grid ---
// 512 threads (8 waves).  Softmax part: per-wave 32x32 sub-tile; staging by
// tid<256 only; softmax 8 lanes/row.  v-GEMM: per-wave 64x32, 2 async16/thr.
__global__ __launch_bounds__(512) void gemm_sm_v(
    const short* A0, const short* A1,       // 8192 x 1024 bf16 (phase, amp)
    const short* Tok,                       // 4 x 128 x 1024 bf16 tokens
    const short* Wall,                      // 4 x 1024 x 1024 bf16 weights
    const float* bt1, const float* bt2,     // b_t2f, b_t2f2
    short* __restrict__ awb,                // 2 x 8192 x 128 bf16
    short* __restrict__ vrow) {             // 2 x 128 x 1024 bf16
  __shared__ __align__(16) char smem[37120];
  const int z = blockIdx.z;
  const int tid = threadIdx.x;
  const int wave = tid >> 6, lane = tid & 63;
  const int m16 = lane & 15, quad = lane >> 4;
  const int fcol = ((quad ^ ((m16 >> 1) & 3)) * 8) + m16 * 32;

  if (blockIdx.x >= 128) {                          // ---- v-GEMM part (BK=32) --
    const int jbBlk = blockIdx.x - 128;             // column block 0..7
    const short* A = Tok + (size_t)(2 + z) * 128 * 1024;   // shifted tokens
    const short* B = Wall + (size_t)z * 1024 * 1024;       // w_t2f / w_t2f2
    const float* bias = z ? bt2 : bt1;
    short* C = vrow + (size_t)z * 128 * 1024;
    const int K = 1024;
    short* As = (short*)smem;                       // 128 x 32
    short* Bs = (short*)(smem + 8192);              // 128 x 32
    const int wm = (wave & 1) * 64, wn = (wave >> 1) * 32;
    f32x4 acc[4][2];
#pragma unroll
    for (int i = 0; i < 4; ++i)
#pragma unroll
      for (int j = 0; j < 2; ++j) acc[i][j] = (f32x4){0.f, 0.f, 0.f, 0.f};
    const int r0v = tid >> 2;                       // 0..127
    const int cswv = (((tid & 3) ^ ((r0v >> 1) & 3)) * 8);
    const short* aSrc = A + (size_t)r0v * K + cswv;
    const short* bSrc = B + (size_t)(jbBlk * 128 + r0v) * K + cswv;
    short* aDst = As + tid * 8;
    short* bDst = Bs + tid * 8;
    for (int k0 = 0; k0 < K; k0 += 32) {
      async16(aSrc + k0, aDst);
      async16(bSrc + k0, bDst);
      __syncthreads();
      bf16x8 af[4], bg[2];
#pragma unroll
      for (int ib = 0; ib < 4; ++ib)
        af[ib] = *(const bf16x8*)(As + (wm + ib * 16) * 32 + fcol);
#pragma unroll
      for (int jb2 = 0; jb2 < 2; ++jb2)
        bg[jb2] = *(const bf16x8*)(Bs + (wn + jb2 * 16) * 32 + fcol);
#pragma unroll
      for (int ib = 0; ib < 4; ++ib)
#pragma unroll
        for (int jb2 = 0; jb2 < 2; ++jb2)
          acc[ib][jb2] = __builtin_amdgcn_mfma_f32_16x16x32_bf16(af[ib], bg[jb2], acc[ib][jb2], 0, 0, 0);
      __syncthreads();
    }
#pragma unroll
    for (int ib = 0; ib < 4; ++ib) {
      const int rowb = wm + ib * 16 + quad * 4;
#pragma unroll
      for (int jb2 = 0; jb2 < 2; ++jb2) {
        const int col = jbBlk * 128 + wn + jb2 * 16 + m16;
        const float bcv = bias[col];
#pragma unroll
        for (int r = 0; r < 4; ++r)
          C[(size_t)(rowb + r) * 1024 + col] = f2bf(acc[ib][jb2][r] + bcv);
      }
    }
    return;
  }

  // ---- softmax-GEMM part, 64x128 tile, BK=64, 8 waves ----
  const short* A = z ? A1 : A0;
  const short* B = Tok + (size_t)z * 128 * 1024;
  const int K = 1024;
  short* As = (short*)smem;                         // [2][64*32]  (8 KB)   K-loop only
  short* Bs = (short*)(smem + 8192);                // [2][128*32] (16 KB)  K-loop only
  float (*ltile)[129] = (float(*)[129])(smem);      // 64x129 f32 (33 KB)  post-loop overlay
  float (*red1)[8] = (float(*)[8])(smem + 33024);   // 64x8 (2 KB)
  float (*red2)[8] = (float(*)[8])(smem + 35072);   // 64x8 (2 KB)
  const int wm = (wave & 1) * 32, wn = (wave >> 1) * 32;
  f32x4 acc[2][2];
#pragma unroll
  for (int i = 0; i < 2; ++i)
#pragma unroll
    for (int j = 0; j < 2; ++j) acc[i][j] = (f32x4){0.f, 0.f, 0.f, 0.f};
  // staging by tid<256 only — identical address pattern to R20
  const int r0s = (tid & 255) >> 2;
  const int csws = (((tid & 3) ^ ((r0s >> 1) & 3)) * 8);
  const short* aSrc  = A + (size_t)(blockIdx.x * 64 + r0s) * K + csws;
  const short* bSrc0 = B + (size_t)r0s * K + csws;
  const short* bSrc1 = bSrc0 + (size_t)64 * K;
  short* aDst0  = As + (tid & 255) * 8;             // sub0: 64x32
  short* aDst1  = As + 2048 + (tid & 255) * 8;      // sub1
  short* bDst00 = Bs + (tid & 255) * 8;             // sub0 rows 0-63
  short* bDst01 = Bs + 2048 + (tid & 255) * 8;      // sub0 rows 64-127
  short* bDst10 = Bs + 4096 + (tid & 255) * 8;      // sub1 rows 0-63
  short* bDst11 = Bs + 6144 + (tid & 255) * 8;      // sub1 rows 64-127
  for (int k0 = 0; k0 < K; k0 += 64) {
    if (tid < 256) {
      async16(aSrc + k0,       aDst0);
      async16(aSrc + k0 + 32,  aDst1);
      async16(bSrc0 + k0,      bDst00);
      async16(bSrc1 + k0,      bDst01);
      async16(bSrc0 + k0 + 32, bDst10);
      async16(bSrc1 + k0 + 32, bDst11);
    }
    __syncthreads();
#pragma unroll
    for (int sub = 0; sub < 2; ++sub) {
      bf16x8 af[2], bg[2];
#pragma unroll
      for (int ib = 0; ib < 2; ++ib)
        af[ib] = *(const bf16x8*)(As + sub * 2048 + (wm + ib * 16) * 32 + fcol);
#pragma unroll
      for (int jb = 0; jb < 2; ++jb)
        bg[jb] = *(const bf16x8*)(Bs + sub * 4096 + (wn + jb * 16) * 32 + fcol);
#pragma unroll
      for (int ib = 0; ib < 2; ++ib)
#pragma unroll
        for (int jb = 0; jb < 2; ++jb)
          acc[ib][jb] = __builtin_amdgcn_mfma_f32_16x16x32_bf16(af[ib], bg[jb], acc[ib][jb], 0, 0, 0);
    }
    __syncthreads();
  }
  // staging region dead; ltile overlays it (ordered by barrier above)
#pragma unroll
  for (int ib = 0; ib < 2; ++ib)
#pragma unroll
    for (int jb = 0; jb < 2; ++jb)
#pragma unroll
      for (int r = 0; r < 4; ++r)
        ltile[wm + ib * 16 + quad * 4 + r][wn + jb * 16 + m16] = acc[ib][jb][r];
  __syncthreads();
  const int row = tid >> 3, l8 = tid & 7;           // 8 lanes/row, 64 rows
  float s = 0.f, q = 0.f;
  for (int c = l8; c < 100; c += 8) { float x = ltile[row][c]; s += x; q += x * x; }
  red1[row][l8] = s; red2[row][l8] = q;
  __syncthreads();
  float ssum = 0.f, qsum = 0.f;
#pragma unroll
  for (int i = 0; i < 8; ++i) { ssum += red1[row][i]; qsum += red2[row][i]; }
  __syncthreads();
  const float mu = ssum * 0.01f;
  const float rinv = rsqrtf(fmaxf(qsum * 0.01f - mu * mu, 0.f) + 1e-5f);
  float mx = -3.4e38f;
  for (int c = l8; c < 100; c += 8) {
    float x = ltile[row][c];
    if (z == 1) x = (x - mu) * rinv;                // instance-norm (amp path)
    x *= 0.03125f;                                  // * C^{-1/2}
    ltile[row][c] = x;
    mx = fmaxf(mx, x);
  }
  red1[row][l8] = mx;
  __syncthreads();
#pragma unroll
  for (int i = 0; i < 8; ++i) mx = fmaxf(mx, red1[row][i]);
  __syncthreads();
  float es = 0.f;
  for (int c = l8; c < 100; c += 8) {
    float e = __expf(ltile[row][c] - mx);
    ltile[row][c] = e; es += e;
  }
  red1[row][l8] = es;
  __syncthreads();
  float tot = 0.f;
#pragma unroll
  for (int i = 0; i < 8; ++i) tot += red1[row][i];
  const float inv = 1.f / tot;
  short* Aout = awb + ((size_t)z * 8192 + (size_t)blockIdx.x * 64 + row) * 128;
  for (int c = l8; c < 100; c += 8)
    if (c >= 1) Aout[c - 1] = f2bf(ltile[row][c] * inv);  // aw[k]=attn[k+1]
  for (int k = l8; k < 128; k += 8)
    if (k >= 99) Aout[k] = 0;                             // zero pad 99..127
}

// ------------- 64x128-tile GEMM (V2T), double-buffered ----------------------
// R24: only 32 blocks on 256 CUs (0 TLP) -> the synchronous K-loop was pure
// exposed HBM latency.  2-buffer pipeline with counted vmcnt: issue next
// buffer's 3 loads, s_waitcnt vmcnt(3) (never 0 in-loop), raw s_barrier +
// sched_barrier(0).  Buffer b re-staged only after the barrier closing the
// compute that read b.
__global__ __launch_bounds__(256) void gemm64(
    const short* A0, const short* A1,       // M x K bf16
    const short* B0, const short* B1,       // 128 x K bf16
    void* C0v, void* C1v, int K, int ldc) {
  const int z = blockIdx.z;
  const short* A = z ? A1 : A0;
  const short* B = z ? B1 : B0;
  void* Cv = z ? C1v : C0v;
  __shared__ __align__(16) short As[2][64 * 32];    // 8 KB
  __shared__ __align__(16) short Bs[2][128 * 32];   // 16 KB
  const int tid = threadIdx.x;
  const int wave = tid >> 6, lane = tid & 63;
  const int m16 = lane & 15, quad = lane >> 4;
  const int wm = (wave & 1) * 32, wn = (wave >> 1) * 64;
  f32x4 acc[2][4];
#pragma unroll
  for (int i = 0; i < 2; ++i)
#pragma unroll
    for (int j = 0; j < 4; ++j) acc[i][j] = (f32x4){0.f, 0.f, 0.f, 0.f};
  const int r0 = tid >> 2;
  const int csw = (((tid & 3) ^ ((r0 >> 1) & 3)) * 8);
  const short* aSrc  = A + (size_t)(blockIdx.x * 64 + r0) * K + csw;
  const short* bSrc0 = B + (size_t)r0 * K + csw;
  const short* bSrc1 = bSrc0 + (size_t)64 * K;
  const int fcol = ((quad ^ ((m16 >> 1) & 3)) * 8) + m16 * 32;
  const int NIT = K >> 5;                           // 32
  // prologue: stage buffer 0 (k0 = 0)
  async16(aSrc,  As[0] + tid * 8);
  async16(bSrc0, Bs[0] + tid * 8);
  async16(bSrc1, Bs[0] + 2048 + tid * 8);
#pragma unroll 1
  for (int it = 0; it < NIT; ++it) {
    const int cur = it & 1;
    if (it + 1 < NIT) {                             // stage next buffer
      const int k0n = (it + 1) << 5;
      async16(aSrc + k0n,  As[cur ^ 1] + tid * 8);
      async16(bSrc0 + k0n, Bs[cur ^ 1] + tid * 8);
      async16(bSrc1 + k0n, Bs[cur ^ 1] + 2048 + tid * 8);
      asm volatile("s_waitcnt vmcnt(3)" ::: "memory");   // oldest 3 = cur's loads
    } else {
      asm volatile("s_waitcnt vmcnt(0)" ::: "memory");
    }
    __builtin_amdgcn_sched_barrier(0);
    __builtin_amdgcn_s_barrier();
    bf16x8 af[2], bg[4];
#pragma unroll
    for (int ib = 0; ib < 2; ++ib)
      af[ib] = *(const bf16x8*)(&As[cur][0] + (wm + ib * 16) * 32 + fcol);
#pragma unroll
    for (int jb = 0; jb < 4; ++jb)
      bg[jb] = *(const bf16x8*)(&Bs[cur][0] + (wn + jb * 16) * 32 + fcol);
#pragma unroll
    for (int ib = 0; ib < 2; ++ib)
#pragma unroll
      for (int jb = 0; jb < 4; ++jb)
        acc[ib][jb] = __builtin_amdgcn_mfma_f32_16x16x32_bf16(af[ib], bg[jb], acc[ib][jb], 0, 0, 0);
    __builtin_amdgcn_sched_barrier(0);
    __builtin_amdgcn_s_barrier();
  }
#pragma unroll
  for (int ib = 0; ib < 2; ++ib) {
    const int rowb = blockIdx.x * 64 + wm + ib * 16 + quad * 4;
#pragma unroll
    for (int jb = 0; jb < 4; ++jb) {
      const int col = wn + jb * 16 + m16;
#pragma unroll
      for (int r = 0; r < 4; ++r)
        ((short*)Cv)[(size_t)(rowb + r) * ldc + col] = f2bf(acc[ib][jb][r]);
    }
  }
}

// ---- dual-K fused GEMM, 256x256 tile, 8-phase schedule (T3+T4+T5) ----------
#define SLOT8(VM, DOSTAGE)                                                   \
  do {                                                                       \
    const short* Asl = &As[k & 3][0];                                        \
    const short* Bsl = &Bs[k & 3][0];                                        \
    const int kp = k + 3;                                                    \
    const short *as0 = nullptr, *as1 = nullptr, *bs0 = nullptr, *bs1 = nullptr; \
    short *ad = nullptr, *bd = nullptr;                                      \
    if (DOSTAGE) {                                                           \
      ad = &As[kp & 3][0]; bd = &Bs[kp & 3][0];                              \
      if (kp < NS1) {                                                        \
        const int c = kp << 5;                                               \
        as0 = A1 + aO1_0 + c; as1 = A1 + aO1_1 + c;                          \
        bs0 = B1 + bO1_0 + c; bs1 = B1 + bO1_1 + c;                          \
      } else {                                                               \
        const int c = (kp - NS1) << 5;                                       \
        as0 = A2 + aO2_0 + c; as1 = A2 + aO2_1 + c;                          \
        bs0 = B2 + bO2_0 + c; bs1 = B2 + bO2_1 + c;                          \
      }                                                                      \
    }                                                                        \
    bf16x8 bg[4], af[4];                                                     \
    /* ---- phase A: bg + af(rows wm..wm+63) + stage A-half of k+3 ---- */   \
    _Pragma("unroll")                                                        \
    for (int jb = 0; jb < 4; ++jb)                                           \
      bg[jb] = *(const bf16x8*)(Bsl + (wn + jb * 16) * 32 + fcol);           \
    _Pragma("unroll")                                                        \
    for (int ib = 0; ib < 4; ++ib)                                           \
      af[ib] = *(const bf16x8*)(Asl + (wm + ib * 16) * 32 + fcol);           \
    if (DOSTAGE) {                                                           \
      async16(as0, ad + tid * 8);                                            \
      async16(as1, ad + 4096 + tid * 8);                                     \
    }                                                                        \
    __builtin_amdgcn_sched_barrier(0);                                       \
    __builtin_amdgcn_s_barrier();                                            \
    asm volatile("s_waitcnt lgkmcnt(0)" ::: "memory");                       \
    __builtin_amdgcn_s_setprio(1);                                           \
    _Pragma("unroll")                                                        \
    for (int ib = 0; ib < 4; ++ib)                                           \
      _Pragma("unroll")                                                      \
      for (int jb = 0; jb < 4; ++jb)                                         \
        acc[ib][jb] = __builtin_amdgcn_mfma_f32_16x16x32_bf16(               \
            af[ib], bg[jb], acc[ib][jb], 0, 0, 0);                           \
    __builtin_amdgcn_s_setprio(0);                                           \
    __builtin_amdgcn_sched_barrier(0);                                       \
    __builtin_amdgcn_s_barrier();                                            \
    /* ---- phase B: af(rows wm+64..wm+127) + stage B-half of k+3 ---- */    \
    _Pragma("unroll")                                                        \
    for (int ib = 0; ib < 4; ++ib)                                           \
      af[ib] = *(const bf16x8*)(Asl + (wm + 64 + ib * 16) * 32 + fcol);      \
    if (DOSTAGE) {                                                           \
      async16(bs0, bd + tid * 8);                                            \
      async16(bs1, bd + 4096 + tid * 8);                                     \
    }                                                                        \
    __builtin_amdgcn_sched_barrier(0);                                       \
    __builtin_amdgcn_s_barrier();                                            \
    asm volatile("s_waitcnt lgkmcnt(0)" ::: "memory");                       \
    __builtin_amdgcn_s_setprio(1);                                           \
    _Pragma("unroll")                                                        \
    for (int ib = 0; ib < 4; ++ib)                                           \
      _Pragma("unroll")                                                      \
      for (int jb = 0; jb < 4; ++jb)                                         \
        acc[ib + 4][jb] = __builtin_amdgcn_mfma_f32_16x16x32_bf16(           \
            af[ib], bg[jb], acc[ib + 4][jb], 0, 0, 0);                       \
    __builtin_amdgcn_s_setprio(0);                                           \
    asm volatile("s_waitcnt vmcnt(" #VM ")" ::: "memory");                   \
    __builtin_amdgcn_sched_barrier(0);                                       \
    __builtin_amdgcn_s_barrier();                                            \
  } while (0)

__global__ __launch_bounds__(512) void gemm256_dual(
    const short* A1_0, const short* A1_1,   // M x K1
    const short* B1_0, const short* B1_1,   // N x K1
    const short* A2_0, const short* A2_1,   // M x K2
    const short* B2_0, const short* B2_1,   // N x K2
    const float* bias0, const float* bias1,
    short* C0, short* C1, int K1, int K2, int ldc) {
  const int z = blockIdx.z;
  const short* A1 = z ? A1_1 : A1_0;
  const short* B1 = z ? B1_1 : B1_0;
  const short* A2 = z ? A2_1 : A2_0;
  const short* B2 = z ? B2_1 : B2_0;
  const float* bias = z ? bias1 : bias0;
  short* C = z ? C1 : C0;
  __shared__ __align__(16) short As[4][8192];       // 4 slots x 256x32 (64 KB)
  __shared__ __align__(16) short Bs[4][8192];       // 4 slots x 256x32 (64 KB)
  const int tid = threadIdx.x;
  const int wave = tid >> 6, lane = tid & 63;
  const int m16 = lane & 15, quad = lane >> 4;
  const int wm = (wave & 1) * 128, wn = (wave >> 1) * 64;
  const int fcol = ((quad ^ ((m16 >> 1) & 3)) * 8) + m16 * 32;
  const int r0 = tid >> 2;                          // 0..127
  const int csw = (((tid & 3) ^ ((r0 >> 1) & 3)) * 8);
  const size_t aO1_0 = (size_t)(blockIdx.x * 256 + r0) * (size_t)K1 + csw;
  const size_t aO1_1 = aO1_0 + (size_t)128 * K1;
  const size_t bO1_0 = (size_t)(blockIdx.y * 256 + r0) * (size_t)K1 + csw;
  const size_t bO1_1 = bO1_0 + (size_t)128 * K1;
  const size_t aO2_0 = (size_t)(blockIdx.x * 256 + r0) * (size_t)K2 + csw;
  const size_t aO2_1 = aO2_0 + (size_t)128 * K2;
  const size_t bO2_0 = (size_t)(blockIdx.y * 256 + r0) * (size_t)K2 + csw;
  const size_t bO2_1 = bO2_0 + (size_t)128 * K2;
  const int NS1 = K1 >> 5;                          // 4
  const int NT  = NS1 + (K2 >> 5);                  // 36
  f32x4 acc[8][4];
#pragma unroll
  for (int i = 0; i < 8; ++i)
#pragma unroll
    for (int j = 0; j < 4; ++j) acc[i][j] = (f32x4){0.f, 0.f, 0.f, 0.f};
  // prologue: stage slots 0..2 fully (12 loads in flight per wave)
#pragma unroll
  for (int k = 0; k < 3; ++k) {
    short* ad = &As[k & 3][0];
    short* bd = &Bs[k & 3][0];
    const short *as0, *as1, *bs0, *bs1;
    if (k < NS1) {
      const int c = k << 5;
      as0 = A1 + aO1_0 + c; as1 = A1 + aO1_1 + c;
      bs0 = B1 + bO1_0 + c; bs1 = B1 + bO1_1 + c;
    } else {
      const int c = (k - NS1) << 5;
      as0 = A2 + aO2_0 + c; as1 = A2 + aO2_1 + c;
      bs0 = B2 + bO2_0 + c; bs1 = B2 + bO2_1 + c;
    }
    async16(as0, ad + tid * 8);
    async16(as1, ad + 4096 + tid * 8);
    async16(bs0, bd + tid * 8);
    async16(bs1, bd + 4096 + tid * 8);
  }
  // gate slot 0: oldest 4 of 12 loads must land
  asm volatile("s_waitcnt vmcnt(8)" ::: "memory");
  __builtin_amdgcn_sched_barrier(0);
  __builtin_amdgcn_s_barrier();
#pragma unroll 1
  for (int k = 0; k < NT - 3; ++k) {                // k = 0..32, always stages
    SLOT8(8, true);
  }
  { const int k = NT - 3; SLOT8(4, false); }        // gate slot NT-2
  { const int k = NT - 2; SLOT8(0, false); }        // gate slot NT-1
  { const int k = NT - 1; SLOT8(0, false); }        // last slot
  // epilogue
#pragma unroll
  for (int ib = 0; ib < 8; ++ib) {
    const int rowb = blockIdx.x * 256 + wm + ib * 16 + quad * 4;
#pragma unroll
    for (int jb = 0; jb < 4; ++jb) {
      const int col = blockIdx.y * 256 + wn + jb * 16 + m16;
      const float bcv = bias[col];
#pragma unroll
      for (int r = 0; r < 4; ++r) {
        const size_t idx = (size_t)(rowb + r) * (size_t)ldc + col;
        C[idx] = f2bf(acc[ib][jb][r] + bcv);
      }
    }
  }
}
#undef SLOT8

// ---- fused inverse: polar->z, FFT8 inv, Hermitian-packed ifft, residual ----
// R21 256-thread version (best-measured; 512-thread variant was neutral).
__global__ __launch_bounds__(256) void inv_fft2_res(const short* __restrict__ dPb,
                                                    const short* __restrict__ dAb,
                                                    const float* __restrict__ feats,
                                                    const float* __restrict__ scalep,
                                                    float* __restrict__ out) {
  __shared__ float2 zb[4][1056];                    // 33.8 KB -> 4 blocks/CU
  const int t = threadIdx.x;
  const int n = blockIdx.x;
  const short* pp = dPb + (size_t)n * 8192;
  const short* ap = dAb + (size_t)n * 8192;
  const float invs = 0.022097086912079608f;         // 1/sqrt(2048)
  const float inv8 = 0.35355339059327373f;          // 1/sqrt(8) (ortho)
  for (int k = t; k < 513; k += 256) {
    float zr[8], zi[8];
#pragma unroll
    for (int b = 0; b < 8; ++b) {
      float p = bf2f(pp[b * 1024 + k]);
      float a = bf2f(ap[b * 1024 + k]) * invs;
      float s, c; __sincosf(p, &s, &c);
      zr[b] = c * a; zi[b] = s * a;
    }
    fft8_inv(zr, zi);                               // Z[bp] = ifft along batch
#pragma unroll
    for (int l = 0; l < 4; ++l) {
      const int bp = 2 * l;                         // pair (bp, bp+1)
      float ax = zr[bp] * inv8,     ay = zi[bp] * inv8;
      float bx = zr[bp + 1] * inv8, by = zi[bp + 1] * inv8;
      zb[l][PADi(k)] = make_float2(ax - by, ay + bx);   // Y = Za + i*Zb
      if (k >= 1 && k <= 511)
        zb[l][PADi(1024 - k)] = make_float2(ax + by, bx - ay);
    }
  }
  __syncthreads();
  fft1024xN<1, 4>(zb, t);
  const int rt = rev4_8(t);
  const float s = scalep[0] * 0.03125f;             // scale * 1/sqrt(1024)
#pragma unroll
  for (int l = 0; l < 4; ++l) {
    const size_t ob0 = 8192 + ((size_t)n * 8 + 2 * l) * 1024;
    const size_t ob1 = ob0 + 1024;
#pragma unroll
    for (int m = 0; m < 4; ++m) {
      const int nn = 256 * m + t;
      float2 y = zb[l][PADi(4 * rt + m)];
      out[ob0 + nn] = feats[ob0 + nn] + y.x * s;
      out[ob1 + nn] = feats[ob1 + nn] + y.y * s;
    }
  }
}

// ---------------------------------------------------------------------------
extern "C" void kernel_launch(void* const* d_in, const int* in_sizes, int n_in,
                              void* d_out, int out_size, void* d_ws, size_t ws_size,
                              hipStream_t stream) {
  const float* feats  = (const float*)d_in[0];
  const float* lt1    = (const float*)d_in[1];
  const float* lt2    = (const float*)d_in[2];
  const float* w_t2f  = (const float*)d_in[3];
  const float* b_t2f  = (const float*)d_in[4];
  const float* w_df   = (const float*)d_in[5];
  const float* b_df   = (const float*)d_in[6];
  const float* w_t2f2 = (const float*)d_in[7];
  const float* b_t2f2 = (const float*)d_in[8];
  const float* w_df2  = (const float*)d_in[9];
  const float* b_df2  = (const float*)d_in[10];
  const float* scalep = (const float*)d_in[11];
  const int*   layerp = (const int*)d_in[12];
  float* out = (float*)d_out;
  (void)in_sizes; (void)n_in; (void)out_size; (void)ws_size;

  const size_t SZ = 8192ull * 1024ull;              // 8,388,608 elements
  short* Pa   = (short*)d_ws;                       // phase bf16 (16 MB)
  short* Pb   = Pa + SZ;                            // amp   bf16 (16 MB)
  short* awb  = Pb + SZ;                            // aw bf16, 2x8192x128 (4 MB)
  short* Tok  = awb + 2ull * 8192 * 128;            // tokens bf16, 4x128x1024 (1 MB)
  short* Wall = Tok + 4ull * 128 * 1024;            // weights bf16, 4x1024x1024 (8 MB)
  short* vrow = Wall + 4ull * 1024 * 1024;          // v row-major, 2x128x1024 (0.5 MB)
  short* V2T  = vrow + 2ull * 128 * 1024;           // w_df@v^T, 2x1024x128 (0.5 MB)
  short* dP   = V2T + 2ull * 1024 * 128;            // d_phase bf16 (16 MB)
  short* dA   = dP + SZ;                            // d_amp bf16 (16 MB)

  // 1: fwd fft2 + amp/phase (blocks 0..1023) + weight/token convert + cls copy
  fwd_fft2_amp_conv<<<dim3(5664), dim3(256), 0, stream>>>(
      feats, Pb, Pa, w_t2f, w_t2f2, w_df, w_df2, lt1, lt2, layerp,
      Wall, Tok, out);
  // 2: GEMM1+in+softmax (x<128, 64x128 tiles) and v-GEMM (x>=128), 512 thr
  gemm_sm_v<<<dim3(136, 1, 2), dim3(512), 0, stream>>>(
      Pa, Pb, Tok, Wall, b_t2f, b_t2f2, awb, vrow);
  // 3: V2T = w_df @ v^T  (M=1024, N=128, K=1024), bf16, ldc=128, dbuf pipeline
  gemm64<<<dim3(16, 1, 2), dim3(256), 0, stream>>>(
      Wall + 2 * 1024 * 1024, Wall + 3 * 1024 * 1024,
      vrow, vrow + 128 * 1024,
      V2T, V2T + 1024 * 128, 1024, 128);
  // 4: d = aw @ V2T^T + P @ w_df^T + b_df  (M=8192, N=1024, K=128+1024), bf16
  gemm256_dual<<<dim3(32, 4, 2), dim3(512), 0, stream>>>(
      awb, awb + 8192 * 128, V2T, V2T + 1024 * 128,
      Pa, Pb, Wall + 2 * 1024 * 1024, Wall + 3 * 1024 * 1024,
      b_df, b_df2, dP, dA, 128, 1024, 1024);
  // 5: fused inverse: polar -> ifft8 -> ifft_c -> residual (1 block/n)
  inv_fft2_res<<<dim3(1024), dim3(256), 0, stream>>>(dP, dA, feats, scalep, out);
}

// Round 15
// 243.090 us; speedup vs baseline: 1.0144x; 1.0086x over previous
//
#include <hip/hip_runtime.h>
#include <cstddef>

// ---------------------------------------------------------------------------
// Reins layer on MI355X — round 25 (final consolidation).
// R24 = best (245.2).  R25 single micro-change: fwd epilogue transcendentals
// use raw-rate instructions — __frcp_rn -> __builtin_amdgcn_rcpf and sqrtf ->
// __builtin_amdgcn_sqrtf (1-ulp, no Newton fixup).  Error ~2^-22 relative,
// five orders below fast_atan2's own 1.5e-4 polynomial error; swallowed by
// bf16 output rounding.  All else byte-identical to R24.
// Session ledger: gemm256_dual parked at 26-28% MfmaUtil across 5 schedule
// variants (MFMA floor 15.5us vs ~46; unlock needs asm-level pipelining);
// FFTs latency-chain-bound (wave-count and barrier changes neutral).
// ---------------------------------------------------------------------------

using bf16x8 = __attribute__((ext_vector_type(8))) short;   // 8 bf16 in 4 VGPRs
using f32x4  = __attribute__((ext_vector_type(4))) float;

__device__ inline short f2bf(float f) {
  union { float f; unsigned u; } v; v.f = f;
  unsigned r = v.u + 0x7FFFu + ((v.u >> 16) & 1u);  // round-to-nearest-even
  return (short)(r >> 16);
}
__device__ inline float bf2f(short s) {
  union { unsigned u; float f; } v; v.u = ((unsigned)(unsigned short)s) << 16;
  return v.f;
}
__device__ inline void async16(const void* g, void* l) {
  __builtin_amdgcn_global_load_lds(
      (const __attribute__((address_space(1))) void*)g,
      (__attribute__((address_space(3))) void*)l, 16, 0, 0);
}
__device__ inline float fast_atan2(float y, float x) {   // max err ~1.5e-4 rad
  float ax = fabsf(x), ay = fabsf(y);
  float mx = fmaxf(ax, ay), mn = fminf(ax, ay);
  float a = mn * __builtin_amdgcn_rcpf(mx);              // raw v_rcp_f32 (1 ulp)
  float s = a * a;
  float r = fmaf(fmaf(fmaf(-0.0464964749f, s, 0.15931422f), s, -0.327622764f),
                 s * a, a);
  if (ay > ax) r = 1.5707963267948966f - r;
  if (x < 0.f) r = 3.14159265358979f - r;
  return (y < 0.f) ? -r : r;
}

__device__ inline int PADi(int i) { return i + (i >> 5); }   // LDS anti-conflict
__device__ inline int rev4_8(int t) {                         // reverse 4 base-4 digits
  return ((t & 3) << 6) | (((t >> 2) & 3) << 4) | (((t >> 4) & 3) << 2) | ((t >> 6) & 3);
}

// ---- radix-2 DIF FFT8, natural-order in & out ------------------------------
__device__ inline void fft8_fwd(float* xr, float* xi) {      // X[k]=Σx e^{-2πikb/8}
  const float r = 0.70710678118654752f;
  float ar[4], ai[4], br[4], bi[4], tr, ti;
  ar[0]=xr[0]+xr[4]; ai[0]=xi[0]+xi[4]; br[0]=xr[0]-xr[4]; bi[0]=xi[0]-xi[4];
  ar[1]=xr[1]+xr[5]; ai[1]=xi[1]+xi[5];
  tr=xr[1]-xr[5]; ti=xi[1]-xi[5]; br[1]=(tr+ti)*r; bi[1]=(ti-tr)*r;   // *(1-i)r
  ar[2]=xr[2]+xr[6]; ai[2]=xi[2]+xi[6];
  tr=xr[2]-xr[6]; ti=xi[2]-xi[6]; br[2]=ti; bi[2]=-tr;                // *(-i)
  ar[3]=xr[3]+xr[7]; ai[3]=xi[3]+xi[7];
  tr=xr[3]-xr[7]; ti=xi[3]-xi[7]; br[3]=(ti-tr)*r; bi[3]=-(tr+ti)*r;  // *-(1+i)r
  float u0r=ar[0]+ar[2], u0i=ai[0]+ai[2], u1r=ar[1]+ar[3], u1i=ai[1]+ai[3];
  float v0r=ar[0]-ar[2], v0i=ai[0]-ai[2];
  tr=ar[1]-ar[3]; ti=ai[1]-ai[3];
  float v1r=ti, v1i=-tr;                                              // *(-i)
  xr[0]=u0r+u1r; xi[0]=u0i+u1i; xr[4]=u0r-u1r; xi[4]=u0i-u1i;
  xr[2]=v0r+v1r; xi[2]=v0i+v1i; xr[6]=v0r-v1r; xi[6]=v0i-v1i;
  u0r=br[0]+br[2]; u0i=bi[0]+bi[2]; u1r=br[1]+br[3]; u1i=bi[1]+bi[3];
  v0r=br[0]-br[2]; v0i=bi[0]-bi[2];
  tr=br[1]-br[3]; ti=bi[1]-bi[3];
  v1r=ti; v1i=-tr;
  xr[1]=u0r+u1r; xi[1]=u0i+u1i; xr[5]=u0r-u1r; xi[5]=u0i-u1i;
  xr[3]=v0r+v1r; xi[3]=v0i+v1i; xr[7]=v0r-v1r; xi[7]=v0i-v1i;
}
__device__ inline void fft8_inv(float* xr, float* xi) {      // X[k]=Σx e^{+2πikb/8}
  const float r = 0.70710678118654752f;
  float ar[4], ai[4], br[4], bi[4], tr, ti;
  ar[0]=xr[0]+xr[4]; ai[0]=xi[0]+xi[4]; br[0]=xr[0]-xr[4]; bi[0]=xi[0]-xi[4];
  ar[1]=xr[1]+xr[5]; ai[1]=xi[1]+xi[5];
  tr=xr[1]-xr[5]; ti=xi[1]-xi[5]; br[1]=(tr-ti)*r; bi[1]=(tr+ti)*r;   // *(1+i)r
  ar[2]=xr[2]+xr[6]; ai[2]=xi[2]+xi[6];
  tr=xr[2]-xr[6]; ti=xi[2]-xi[6]; br[2]=-ti; bi[2]=tr;                // *(+i)
  ar[3]=xr[3]+xr[7]; ai[3]=xi[3]+xi[7];
  tr=xr[3]-xr[7]; ti=xi[3]-xi[7]; br[3]=-(tr+ti)*r; bi[3]=(tr-ti)*r;  // *(-1+i)r
  float u0r=ar[0]+ar[2], u0i=ai[0]+ai[2], u1r=ar[1]+ar[3], u1i=ai[1]+ai[3];
  float v0r=ar[0]-ar[2], v0i=ai[0]-ai[2];
  tr=ar[1]-ar[3]; ti=ai[1]-ai[3];
  float v1r=-ti, v1i=tr;                                              // *(+i)
  xr[0]=u0r+u1r; xi[0]=u0i+u1i; xr[4]=u0r-u1r; xi[4]=u0i-u1i;
  xr[2]=v0r+v1r; xi[2]=v0i+v1i; xr[6]=v0r-v1r; xi[6]=v0i-v1i;
  u0r=br[0]+br[2]; u0i=bi[0]+bi[2]; u1r=br[1]+br[3]; u1i=bi[1]+bi[3];
  v0r=br[0]-br[2]; v0i=bi[0]-bi[2];
  tr=br[1]-br[3]; ti=bi[1]-bi[3];
  v1r=-ti; v1i=tr;
  xr[1]=u0r+u1r; xi[1]=u0i+u1i; xr[5]=u0r-u1r; xi[5]=u0i-u1i;
  xr[3]=v0r+v1r; xi[3]=v0i+v1i; xr[7]=v0r-v1r; xi[7]=v0i-v1i;
}

// 1024-pt in-place radix-4 DIF, NP interleaved FFTs sharing barriers.
// Stage 0 mixes cross-wave -> block barrier.  Stages 1..4 are wave-local
// (wave w touches only elements 256w..256w+255) -> wave_barrier only.
// Final block barrier before cross-wave epilogue readers.
template <int SIGN, int NP>
__device__ inline void fft1024xN(float2 (*zb)[1056], int t) {
#pragma unroll
  for (int s = 0; s < 5; ++s) {
    const int Q = 256 >> (2 * s);
    const int j = t & (Q - 1);
    const int i0 = ((t & ~(Q - 1)) << 2) + j;
    const float ang = (float)SIGN * 6.283185307179586f * (float)j / (float)(4 * Q);
    float s1, c1; __sincosf(ang, &s1, &c1);
    const float c2 = c1 * c1 - s1 * s1, s2 = 2.f * c1 * s1;
    const float c3 = c2 * c1 - s2 * s1, s3 = c2 * s1 + s2 * c1;
#pragma unroll
    for (int p = 0; p < NP; ++p) {
      float2* z = zb[p];
      float2 x0 = z[PADi(i0)];
      float2 x1 = z[PADi(i0 + Q)];
      float2 x2 = z[PADi(i0 + 2 * Q)];
      float2 x3 = z[PADi(i0 + 3 * Q)];
      float t0x = x0.x + x2.x, t0y = x0.y + x2.y;
      float t1x = x0.x - x2.x, t1y = x0.y - x2.y;
      float t2x = x1.x + x3.x, t2y = x1.y + x3.y;
      float t3x = x1.x - x3.x, t3y = x1.y - x3.y;
      float u0x = t0x + t2x, u0y = t0y + t2y;
      float u2x = t0x - t2x, u2y = t0y - t2y;
      float u1x, u1y, u3x, u3y;
      if (SIGN < 0) { u1x = t1x + t3y; u1y = t1y - t3x; u3x = t1x - t3y; u3y = t1y + t3x; }
      else          { u1x = t1x - t3y; u1y = t1y + t3x; u3x = t1x + t3y; u3y = t1y - t3x; }
      z[PADi(i0)]         = make_float2(u0x, u0y);
      z[PADi(i0 + Q)]     = make_float2(u1x * c1 - u1y * s1, u1x * s1 + u1y * c1);
      z[PADi(i0 + 2 * Q)] = make_float2(u2x * c2 - u2y * s2, u2x * s2 + u2y * c2);
      z[PADi(i0 + 3 * Q)] = make_float2(u3x * c3 - u3y * s3, u3x * s3 + u3y * c3);
    }
    if (s == 0 || s == 4) __syncthreads();          // cross-wave boundaries only
    else                  __builtin_amdgcn_wave_barrier();  // compile-time order pin
  }
}

// ---- 1. fused fwd fft2 + amp/phase + conv work as extra blocks -------------
__global__ __launch_bounds__(256) void fwd_fft2_amp_conv(
    const float* __restrict__ feats,
    short* __restrict__ ampb, short* __restrict__ phaseb,
    const float* __restrict__ w1, const float* __restrict__ w2,
    const float* __restrict__ w3, const float* __restrict__ w4,
    const float* __restrict__ lt1, const float* __restrict__ lt2,
    const int* __restrict__ layerp,
    short* __restrict__ Wdst, short* __restrict__ Tdst,
    float* __restrict__ out) {
  if (blockIdx.x >= 1024) {                         // ---- conv part ----
    const int id = blockIdx.x - 1024;
    const int t4 = threadIdx.x * 4;
    if (id < 4096) {                                // weights: 4 x 1024 rows
      const int z = id >> 10, row = id & 1023;
      const float* W = (z == 0 ? w1 : z == 1 ? w2 : z == 2 ? w3 : w4)
                       + (size_t)row * 1024;
      short* D = Wdst + ((size_t)z * 1024 + row) * 1024;
      float4 v = *(const float4*)(W + t4);
      D[t4] = f2bf(v.x); D[t4 + 1] = f2bf(v.y); D[t4 + 2] = f2bf(v.z); D[t4 + 3] = f2bf(v.w);
    } else if (id < 4608) {                         // tokens: 4 x 128 rows
      const int i2 = id - 4096;
      const int zz = i2 >> 7, row = i2 & 127;
      const int z = zz & 1, shift = zz >> 1;
      short* D = Tdst + ((size_t)zz * 128 + row) * 1024;
      if (row + shift < 100) {
        const float* S = (z ? lt2 : lt1) + (size_t)layerp[0] * 102400
                         + (size_t)(row + shift) * 1024;
        float4 v = *(const float4*)(S + t4);
        D[t4] = f2bf(v.x); D[t4 + 1] = f2bf(v.y); D[t4 + 2] = f2bf(v.z); D[t4 + 3] = f2bf(v.w);
      } else {
        D[t4] = 0; D[t4 + 1] = 0; D[t4 + 2] = 0; D[t4 + 3] = 0;
      }
    } else {                                        // cls: 32 blocks x 256
      const int i = (id - 4608) * 256 + threadIdx.x;
      out[i] = feats[i];
    }
    return;
  }
  // ---- FFT part ----
  __shared__ float2 zb[4][1056];                    // 33.8 KB
  const int t = threadIdx.x;
  const int n = blockIdx.x;
  const float* base = feats + 8192 + (size_t)n * 8192;
#pragma unroll
  for (int p = 0; p < 4; ++p) {
    const float* x0 = base + (size_t)(2 * p) * 1024;
    const float* x1 = x0 + 1024;
#pragma unroll
    for (int m = 0; m < 4; ++m) {
      const int c = t + 256 * m;
      zb[p][PADi(c)] = make_float2(x0[c], x1[c]);
    }
  }
  __syncthreads();
  fft1024xN<-1, 4>(zb, t);
  const int rt = rev4_8(t);
  short* ab = ampb + (size_t)n * 8192;
  short* pb = phaseb + (size_t)n * 8192;
#pragma unroll
  for (int m = 0; m < 4; ++m) {
    const int k = 256 * m + t;
    const int kk = (1024 - k) & 1023;
    const int pos  = 4 * rt + m;
    const int pos2 = 4 * rev4_8(kk & 255) + (kk >> 8);
    float xr[8], xi[8];
#pragma unroll
    for (int p = 0; p < 4; ++p) {
      float2 Z = zb[p][PADi(pos)];
      float2 W = zb[p][PADi(pos2)];
      xr[2 * p]     = 0.5f * (Z.x + W.x);
      xi[2 * p]     = 0.5f * (Z.y - W.y);
      xr[2 * p + 1] = 0.5f * (Z.y + W.y);
      xi[2 * p + 1] = 0.5f * (W.x - Z.x);
    }
    fft8_fwd(xr, xi);                               // X[kb] along batch dim
#pragma unroll
    for (int kb = 0; kb < 8; ++kb) {
      float sr = xr[kb], si = xi[kb];
      float r2 = sr * sr + si * si;
      if (r2 < 1e-5f) r2 = 1e-5f;                   // _replace_denormals(re^2+im^2)
      float a = __builtin_amdgcn_sqrtf(r2);         // raw v_sqrt_f32 (1 ulp)
      float rr = (sr < 1e-5f && sr > -1e-5f) ? 1e-5f : sr;
      float ph = fast_atan2(si, rr);
      ab[kb * 1024 + k] = f2bf(a);
      pb[kb * 1024 + k] = f2bf(ph);
    }
  }
}

// ---- 2. GEMM1+softmax (x<128, 64x128 tile) and v-GEMM (x>=128), one grid ---
// 512 threads (8 waves).  Softmax part: per-wave 32x32 sub-tile; staging by
// tid<256 only; softmax 8 lanes/row.  v-GEMM: per-wave 64x32, 2 async16/thr.
__global__ __launch_bounds__(512) void gemm_sm_v(
    const short* A0, const short* A1,       // 8192 x 1024 bf16 (phase, amp)
    const short* Tok,                       // 4 x 128 x 1024 bf16 tokens
    const short* Wall,                      // 4 x 1024 x 1024 bf16 weights
    const float* bt1, const float* bt2,     // b_t2f, b_t2f2
    short* __restrict__ awb,                // 2 x 8192 x 128 bf16
    short* __restrict__ vrow) {             // 2 x 128 x 1024 bf16
  __shared__ __align__(16) char smem[37120];
  const int z = blockIdx.z;
  const int tid = threadIdx.x;
  const int wave = tid >> 6, lane = tid & 63;
  const int m16 = lane & 15, quad = lane >> 4;
  const int fcol = ((quad ^ ((m16 >> 1) & 3)) * 8) + m16 * 32;

  if (blockIdx.x >= 128) {                          // ---- v-GEMM part (BK=32) --
    const int jbBlk = blockIdx.x - 128;             // column block 0..7
    const short* A = Tok + (size_t)(2 + z) * 128 * 1024;   // shifted tokens
    const short* B = Wall + (size_t)z * 1024 * 1024;       // w_t2f / w_t2f2
    const float* bias = z ? bt2 : bt1;
    short* C = vrow + (size_t)z * 128 * 1024;
    const int K = 1024;
    short* As = (short*)smem;                       // 128 x 32
    short* Bs = (short*)(smem + 8192);              // 128 x 32
    const int wm = (wave & 1) * 64, wn = (wave >> 1) * 32;
    f32x4 acc[4][2];
#pragma unroll
    for (int i = 0; i < 4; ++i)
#pragma unroll
      for (int j = 0; j < 2; ++j) acc[i][j] = (f32x4){0.f, 0.f, 0.f, 0.f};
    const int r0v = tid >> 2;                       // 0..127
    const int cswv = (((tid & 3) ^ ((r0v >> 1) & 3)) * 8);
    const short* aSrc = A + (size_t)r0v * K + cswv;
    const short* bSrc = B + (size_t)(jbBlk * 128 + r0v) * K + cswv;
    short* aDst = As + tid * 8;
    short* bDst = Bs + tid * 8;
    for (int k0 = 0; k0 < K; k0 += 32) {
      async16(aSrc + k0, aDst);
      async16(bSrc + k0, bDst);
      __syncthreads();
      bf16x8 af[4], bg[2];
#pragma unroll
      for (int ib = 0; ib < 4; ++ib)
        af[ib] = *(const bf16x8*)(As + (wm + ib * 16) * 32 + fcol);
#pragma unroll
      for (int jb2 = 0; jb2 < 2; ++jb2)
        bg[jb2] = *(const bf16x8*)(Bs + (wn + jb2 * 16) * 32 + fcol);
#pragma unroll
      for (int ib = 0; ib < 4; ++ib)
#pragma unroll
        for (int jb2 = 0; jb2 < 2; ++jb2)
          acc[ib][jb2] = __builtin_amdgcn_mfma_f32_16x16x32_bf16(af[ib], bg[jb2], acc[ib][jb2], 0, 0, 0);
      __syncthreads();
    }
#pragma unroll
    for (int ib = 0; ib < 4; ++ib) {
      const int rowb = wm + ib * 16 + quad * 4;
#pragma unroll
      for (int jb2 = 0; jb2 < 2; ++jb2) {
        const int col = jbBlk * 128 + wn + jb2 * 16 + m16;
        const float bcv = bias[col];
#pragma unroll
        for (int r = 0; r < 4; ++r)
          C[(size_t)(rowb + r) * 1024 + col] = f2bf(acc[ib][jb2][r] + bcv);
      }
    }
    return;
  }

  // ---- softmax-GEMM part, 64x128 tile, BK=64, 8 waves ----
  const short* A = z ? A1 : A0;
  const short* B = Tok + (size_t)z * 128 * 1024;
  const int K = 1024;
  short* As = (short*)smem;                         // [2][64*32]  (8 KB)   K-loop only
  short* Bs = (short*)(smem + 8192);                // [2][128*32] (16 KB)  K-loop only
  float (*ltile)[129] = (float(*)[129])(smem);      // 64x129 f32 (33 KB)  post-loop overlay
  float (*red1)[8] = (float(*)[8])(smem + 33024);   // 64x8 (2 KB)
  float (*red2)[8] = (float(*)[8])(smem + 35072);   // 64x8 (2 KB)
  const int wm = (wave & 1) * 32, wn = (wave >> 1) * 32;
  f32x4 acc[2][2];
#pragma unroll
  for (int i = 0; i < 2; ++i)
#pragma unroll
    for (int j = 0; j < 2; ++j) acc[i][j] = (f32x4){0.f, 0.f, 0.f, 0.f};
  // staging by tid<256 only — identical address pattern to R20
  const int r0s = (tid & 255) >> 2;
  const int csws = (((tid & 3) ^ ((r0s >> 1) & 3)) * 8);
  const short* aSrc  = A + (size_t)(blockIdx.x * 64 + r0s) * K + csws;
  const short* bSrc0 = B + (size_t)r0s * K + csws;
  const short* bSrc1 = bSrc0 + (size_t)64 * K;
  short* aDst0  = As + (tid & 255) * 8;             // sub0: 64x32
  short* aDst1  = As + 2048 + (tid & 255) * 8;      // sub1
  short* bDst00 = Bs + (tid & 255) * 8;             // sub0 rows 0-63
  short* bDst01 = Bs + 2048 + (tid & 255) * 8;      // sub0 rows 64-127
  short* bDst10 = Bs + 4096 + (tid & 255) * 8;      // sub1 rows 0-63
  short* bDst11 = Bs + 6144 + (tid & 255) * 8;      // sub1 rows 64-127
  for (int k0 = 0; k0 < K; k0 += 64) {
    if (tid < 256) {
      async16(aSrc + k0,       aDst0);
      async16(aSrc + k0 + 32,  aDst1);
      async16(bSrc0 + k0,      bDst00);
      async16(bSrc1 + k0,      bDst01);
      async16(bSrc0 + k0 + 32, bDst10);
      async16(bSrc1 + k0 + 32, bDst11);
    }
    __syncthreads();
#pragma unroll
    for (int sub = 0; sub < 2; ++sub) {
      bf16x8 af[2], bg[2];
#pragma unroll
      for (int ib = 0; ib < 2; ++ib)
        af[ib] = *(const bf16x8*)(As + sub * 2048 + (wm + ib * 16) * 32 + fcol);
#pragma unroll
      for (int jb = 0; jb < 2; ++jb)
        bg[jb] = *(const bf16x8*)(Bs + sub * 4096 + (wn + jb * 16) * 32 + fcol);
#pragma unroll
      for (int ib = 0; ib < 2; ++ib)
#pragma unroll
        for (int jb = 0; jb < 2; ++jb)
          acc[ib][jb] = __builtin_amdgcn_mfma_f32_16x16x32_bf16(af[ib], bg[jb], acc[ib][jb], 0, 0, 0);
    }
    __syncthreads();
  }
  // staging region dead; ltile overlays it (ordered by barrier above)
#pragma unroll
  for (int ib = 0; ib < 2; ++ib)
#pragma unroll
    for (int jb = 0; jb < 2; ++jb)
#pragma unroll
      for (int r = 0; r < 4; ++r)
        ltile[wm + ib * 16 + quad * 4 + r][wn + jb * 16 + m16] = acc[ib][jb][r];
  __syncthreads();
  const int row = tid >> 3, l8 = tid & 7;           // 8 lanes/row, 64 rows
  float s = 0.f, q = 0.f;
  for (int c = l8; c < 100; c += 8) { float x = ltile[row][c]; s += x; q += x * x; }
  red1[row][l8] = s; red2[row][l8] = q;
  __syncthreads();
  float ssum = 0.f, qsum = 0.f;
#pragma unroll
  for (int i = 0; i < 8; ++i) { ssum += red1[row][i]; qsum += red2[row][i]; }
  __syncthreads();
  const float mu = ssum * 0.01f;
  const float rinv = rsqrtf(fmaxf(qsum * 0.01f - mu * mu, 0.f) + 1e-5f);
  float mx = -3.4e38f;
  for (int c = l8; c < 100; c += 8) {
    float x = ltile[row][c];
    if (z == 1) x = (x - mu) * rinv;                // instance-norm (amp path)
    x *= 0.03125f;                                  // * C^{-1/2}
    ltile[row][c] = x;
    mx = fmaxf(mx, x);
  }
  red1[row][l8] = mx;
  __syncthreads();
#pragma unroll
  for (int i = 0; i < 8; ++i) mx = fmaxf(mx, red1[row][i]);
  __syncthreads();
  float es = 0.f;
  for (int c = l8; c < 100; c += 8) {
    float e = __expf(ltile[row][c] - mx);
    ltile[row][c] = e; es += e;
  }
  red1[row][l8] = es;
  __syncthreads();
  float tot = 0.f;
#pragma unroll
  for (int i = 0; i < 8; ++i) tot += red1[row][i];
  const float inv = 1.f / tot;
  short* Aout = awb + ((size_t)z * 8192 + (size_t)blockIdx.x * 64 + row) * 128;
  for (int c = l8; c < 100; c += 8)
    if (c >= 1) Aout[c - 1] = f2bf(ltile[row][c] * inv);  // aw[k]=attn[k+1]
  for (int k = l8; k < 128; k += 8)
    if (k >= 99) Aout[k] = 0;                             // zero pad 99..127
}

// ------------- 64x128-tile GEMM (V2T), double-buffered ----------------------
__global__ __launch_bounds__(256) void gemm64(
    const short* A0, const short* A1,       // M x K bf16
    const short* B0, const short* B1,       // 128 x K bf16
    void* C0v, void* C1v, int K, int ldc) {
  const int z = blockIdx.z;
  const short* A = z ? A1 : A0;
  const short* B = z ? B1 : B0;
  void* Cv = z ? C1v : C0v;
  __shared__ __align__(16) short As[2][64 * 32];    // 8 KB
  __shared__ __align__(16) short Bs[2][128 * 32];   // 16 KB
  const int tid = threadIdx.x;
  const int wave = tid >> 6, lane = tid & 63;
  const int m16 = lane & 15, quad = lane >> 4;
  const int wm = (wave & 1) * 32, wn = (wave >> 1) * 64;
  f32x4 acc[2][4];
#pragma unroll
  for (int i = 0; i < 2; ++i)
#pragma unroll
    for (int j = 0; j < 4; ++j) acc[i][j] = (f32x4){0.f, 0.f, 0.f, 0.f};
  const int r0 = tid >> 2;
  const int csw = (((tid & 3) ^ ((r0 >> 1) & 3)) * 8);
  const short* aSrc  = A + (size_t)(blockIdx.x * 64 + r0) * K + csw;
  const short* bSrc0 = B + (size_t)r0 * K + csw;
  const short* bSrc1 = bSrc0 + (size_t)64 * K;
  const int fcol = ((quad ^ ((m16 >> 1) & 3)) * 8) + m16 * 32;
  const int NIT = K >> 5;                           // 32
  // prologue: stage buffer 0 (k0 = 0)
  async16(aSrc,  As[0] + tid * 8);
  async16(bSrc0, Bs[0] + tid * 8);
  async16(bSrc1, Bs[0] + 2048 + tid * 8);
#pragma unroll 1
  for (int it = 0; it < NIT; ++it) {
    const int cur = it & 1;
    if (it + 1 < NIT) {                             // stage next buffer
      const int k0n = (it + 1) << 5;
      async16(aSrc + k0n,  As[cur ^ 1] + tid * 8);
      async16(bSrc0 + k0n, Bs[cur ^ 1] + tid * 8);
      async16(bSrc1 + k0n, Bs[cur ^ 1] + 2048 + tid * 8);
      asm volatile("s_waitcnt vmcnt(3)" ::: "memory");   // oldest 3 = cur's loads
    } else {
      asm volatile("s_waitcnt vmcnt(0)" ::: "memory");
    }
    __builtin_amdgcn_sched_barrier(0);
    __builtin_amdgcn_s_barrier();
    bf16x8 af[2], bg[4];
#pragma unroll
    for (int ib = 0; ib < 2; ++ib)
      af[ib] = *(const bf16x8*)(&As[cur][0] + (wm + ib * 16) * 32 + fcol);
#pragma unroll
    for (int jb = 0; jb < 4; ++jb)
      bg[jb] = *(const bf16x8*)(&Bs[cur][0] + (wn + jb * 16) * 32 + fcol);
#pragma unroll
    for (int ib = 0; ib < 2; ++ib)
#pragma unroll
      for (int jb = 0; jb < 4; ++jb)
        acc[ib][jb] = __builtin_amdgcn_mfma_f32_16x16x32_bf16(af[ib], bg[jb], acc[ib][jb], 0, 0, 0);
    __builtin_amdgcn_sched_barrier(0);
    __builtin_amdgcn_s_barrier();
  }
#pragma unroll
  for (int ib = 0; ib < 2; ++ib) {
    const int rowb = blockIdx.x * 64 + wm + ib * 16 + quad * 4;
#pragma unroll
    for (int jb = 0; jb < 4; ++jb) {
      const int col = wn + jb * 16 + m16;
#pragma unroll
      for (int r = 0; r < 4; ++r)
        ((short*)Cv)[(size_t)(rowb + r) * ldc + col] = f2bf(acc[ib][jb][r]);
    }
  }
}

// ---- dual-K fused GEMM, 256x256 tile, 8-phase schedule (T3+T4+T5) ----------
#define SLOT8(VM, DOSTAGE)                                                   \
  do {                                                                       \
    const short* Asl = &As[k & 3][0];                                        \
    const short* Bsl = &Bs[k & 3][0];                                        \
    const int kp = k + 3;                                                    \
    const short *as0 = nullptr, *as1 = nullptr, *bs0 = nullptr, *bs1 = nullptr; \
    short *ad = nullptr, *bd = nullptr;                                      \
    if (DOSTAGE) {                                                           \
      ad = &As[kp & 3][0]; bd = &Bs[kp & 3][0];                              \
      if (kp < NS1) {                                                        \
        const int c = kp << 5;                                               \
        as0 = A1 + aO1_0 + c; as1 = A1 + aO1_1 + c;                          \
        bs0 = B1 + bO1_0 + c; bs1 = B1 + bO1_1 + c;                          \
      } else {                                                               \
        const int c = (kp - NS1) << 5;                                       \
        as0 = A2 + aO2_0 + c; as1 = A2 + aO2_1 + c;                          \
        bs0 = B2 + bO2_0 + c; bs1 = B2 + bO2_1 + c;                          \
      }                                                                      \
    }                                                                        \
    bf16x8 bg[4], af[4];                                                     \
    /* ---- phase A: bg + af(rows wm..wm+63) + stage A-half of k+3 ---- */   \
    _Pragma("unroll")                                                        \
    for (int jb = 0; jb < 4; ++jb)                                           \
      bg[jb] = *(const bf16x8*)(Bsl + (wn + jb * 16) * 32 + fcol);           \
    _Pragma("unroll")                                                        \
    for (int ib = 0; ib < 4; ++ib)                                           \
      af[ib] = *(const bf16x8*)(Asl + (wm + ib * 16) * 32 + fcol);           \
    if (DOSTAGE) {                                                           \
      async16(as0, ad + tid * 8);                                            \
      async16(as1, ad + 4096 + tid * 8);                                     \
    }                                                                        \
    __builtin_amdgcn_sched_barrier(0);                                       \
    __builtin_amdgcn_s_barrier();                                            \
    asm volatile("s_waitcnt lgkmcnt(0)" ::: "memory");                       \
    __builtin_amdgcn_s_setprio(1);                                           \
    _Pragma("unroll")                                                        \
    for (int ib = 0; ib < 4; ++ib)                                           \
      _Pragma("unroll")                                                      \
      for (int jb = 0; jb < 4; ++jb)                                         \
        acc[ib][jb] = __builtin_amdgcn_mfma_f32_16x16x32_bf16(               \
            af[ib], bg[jb], acc[ib][jb], 0, 0, 0);                           \
    __builtin_amdgcn_s_setprio(0);                                           \
    __builtin_amdgcn_sched_barrier(0);                                       \
    __builtin_amdgcn_s_barrier();                                            \
    /* ---- phase B: af(rows wm+64..wm+127) + stage B-half of k+3 ---- */    \
    _Pragma("unroll")                                                        \
    for (int ib = 0; ib < 4; ++ib)                                           \
      af[ib] = *(const bf16x8*)(Asl + (wm + 64 + ib * 16) * 32 + fcol);      \
    if (DOSTAGE) {                                                           \
      async16(bs0, bd + tid * 8);                                            \
      async16(bs1, bd + 4096 + tid * 8);                                     \
    }                                                                        \
    __builtin_amdgcn_sched_barrier(0);                                       \
    __builtin_amdgcn_s_barrier();                                            \
    asm volatile("s_waitcnt lgkmcnt(0)" ::: "memory");                       \
    __builtin_amdgcn_s_setprio(1);                                           \
    _Pragma("unroll")                                                        \
    for (int ib = 0; ib < 4; ++ib)                                           \
      _Pragma("unroll")                                                      \
      for (int jb = 0; jb < 4; ++jb)                                         \
        acc[ib + 4][jb] = __builtin_amdgcn_mfma_f32_16x16x32_bf16(           \
            af[ib], bg[jb], acc[ib + 4][jb], 0, 0, 0);                       \
    __builtin_amdgcn_s_setprio(0);                                           \
    asm volatile("s_waitcnt vmcnt(" #VM ")" ::: "memory");                   \
    __builtin_amdgcn_sched_barrier(0);                                       \
    __builtin_amdgcn_s_barrier();                                            \
  } while (0)

__global__ __launch_bounds__(512) void gemm256_dual(
    const short* A1_0, const short* A1_1,   // M x K1
    const short* B1_0, const short* B1_1,   // N x K1
    const short* A2_0, const short* A2_1,   // M x K2
    const short* B2_0, const short* B2_1,   // N x K2
    const float* bias0, const float* bias1,
    short* C0, short* C1, int K1, int K2, int ldc) {
  const int z = blockIdx.z;
  const short* A1 = z ? A1_1 : A1_0;
  const short* B1 = z ? B1_1 : B1_0;
  const short* A2 = z ? A2_1 : A2_0;
  const short* B2 = z ? B2_1 : B2_0;
  const float* bias = z ? bias1 : bias0;
  short* C = z ? C1 : C0;
  __shared__ __align__(16) short As[4][8192];       // 4 slots x 256x32 (64 KB)
  __shared__ __align__(16) short Bs[4][8192];       // 4 slots x 256x32 (64 KB)
  const int tid = threadIdx.x;
  const int wave = tid >> 6, lane = tid & 63;
  const int m16 = lane & 15, quad = lane >> 4;
  const int wm = (wave & 1) * 128, wn = (wave >> 1) * 64;
  const int fcol = ((quad ^ ((m16 >> 1) & 3)) * 8) + m16 * 32;
  const int r0 = tid >> 2;                          // 0..127
  const int csw = (((tid & 3) ^ ((r0 >> 1) & 3)) * 8);
  const size_t aO1_0 = (size_t)(blockIdx.x * 256 + r0) * (size_t)K1 + csw;
  const size_t aO1_1 = aO1_0 + (size_t)128 * K1;
  const size_t bO1_0 = (size_t)(blockIdx.y * 256 + r0) * (size_t)K1 + csw;
  const size_t bO1_1 = bO1_0 + (size_t)128 * K1;
  const size_t aO2_0 = (size_t)(blockIdx.x * 256 + r0) * (size_t)K2 + csw;
  const size_t aO2_1 = aO2_0 + (size_t)128 * K2;
  const size_t bO2_0 = (size_t)(blockIdx.y * 256 + r0) * (size_t)K2 + csw;
  const size_t bO2_1 = bO2_0 + (size_t)128 * K2;
  const int NS1 = K1 >> 5;                          // 4
  const int NT  = NS1 + (K2 >> 5);                  // 36
  f32x4 acc[8][4];
#pragma unroll
  for (int i = 0; i < 8; ++i)
#pragma unroll
    for (int j = 0; j < 4; ++j) acc[i][j] = (f32x4){0.f, 0.f, 0.f, 0.f};
  // prologue: stage slots 0..2 fully (12 loads in flight per wave)
#pragma unroll
  for (int k = 0; k < 3; ++k) {
    short* ad = &As[k & 3][0];
    short* bd = &Bs[k & 3][0];
    const short *as0, *as1, *bs0, *bs1;
    if (k < NS1) {
      const int c = k << 5;
      as0 = A1 + aO1_0 + c; as1 = A1 + aO1_1 + c;
      bs0 = B1 + bO1_0 + c; bs1 = B1 + bO1_1 + c;
    } else {
      const int c = (k - NS1) << 5;
      as0 = A2 + aO2_0 + c; as1 = A2 + aO2_1 + c;
      bs0 = B2 + bO2_0 + c; bs1 = B2 + bO2_1 + c;
    }
    async16(as0, ad + tid * 8);
    async16(as1, ad + 4096 + tid * 8);
    async16(bs0, bd + tid * 8);
    async16(bs1, bd + 4096 + tid * 8);
  }
  // gate slot 0: oldest 4 of 12 loads must land
  asm volatile("s_waitcnt vmcnt(8)" ::: "memory");
  __builtin_amdgcn_sched_barrier(0);
  __builtin_amdgcn_s_barrier();
#pragma unroll 1
  for (int k = 0; k < NT - 3; ++k) {                // k = 0..32, always stages
    SLOT8(8, true);
  }
  { const int k = NT - 3; SLOT8(4, false); }        // gate slot NT-2
  { const int k = NT - 2; SLOT8(0, false); }        // gate slot NT-1
  { const int k = NT - 1; SLOT8(0, false); }        // last slot
  // epilogue
#pragma unroll
  for (int ib = 0; ib < 8; ++ib) {
    const int rowb = blockIdx.x * 256 + wm + ib * 16 + quad * 4;
#pragma unroll
    for (int jb = 0; jb < 4; ++jb) {
      const int col = blockIdx.y * 256 + wn + jb * 16 + m16;
      const float bcv = bias[col];
#pragma unroll
      for (int r = 0; r < 4; ++r) {
        const size_t idx = (size_t)(rowb + r) * (size_t)ldc + col;
        C[idx] = f2bf(acc[ib][jb][r] + bcv);
      }
    }
  }
}
#undef SLOT8

// ---- fused inverse: polar->z, FFT8 inv, Hermitian-packed ifft, residual ----
__global__ __launch_bounds__(256) void inv_fft2_res(const short* __restrict__ dPb,
                                                    const short* __restrict__ dAb,
                                                    const float* __restrict__ feats,
                                                    const float* __restrict__ scalep,
                                                    float* __restrict__ out) {
  __shared__ float2 zb[4][1056];                    // 33.8 KB -> 4 blocks/CU
  const int t = threadIdx.x;
  const int n = blockIdx.x;
  const short* pp = dPb + (size_t)n * 8192;
  const short* ap = dAb + (size_t)n * 8192;
  const float invs = 0.022097086912079608f;         // 1/sqrt(2048)
  const float inv8 = 0.35355339059327373f;          // 1/sqrt(8) (ortho)
  for (int k = t; k < 513; k += 256) {
    float zr[8], zi[8];
#pragma unroll
    for (int b = 0; b < 8; ++b) {
      float p = bf2f(pp[b * 1024 + k]);
      float a = bf2f(ap[b * 1024 + k]) * invs;
      float s, c; __sincosf(p, &s, &c);
      zr[b] = c * a; zi[b] = s * a;
    }
    fft8_inv(zr, zi);                               // Z[bp] = ifft along batch
#pragma unroll
    for (int l = 0; l < 4; ++l) {
      const int bp = 2 * l;                         // pair (bp, bp+1)
      float ax = zr[bp] * inv8,     ay = zi[bp] * inv8;
      float bx = zr[bp + 1] * inv8, by = zi[bp + 1] * inv8;
      zb[l][PADi(k)] = make_float2(ax - by, ay + bx);   // Y = Za + i*Zb
      if (k >= 1 && k <= 511)
        zb[l][PADi(1024 - k)] = make_float2(ax + by, bx - ay);
    }
  }
  __syncthreads();
  fft1024xN<1, 4>(zb, t);
  const int rt = rev4_8(t);
  const float s = scalep[0] * 0.03125f;             // scale * 1/sqrt(1024)
#pragma unroll
  for (int l = 0; l < 4; ++l) {
    const size_t ob0 = 8192 + ((size_t)n * 8 + 2 * l) * 1024;
    const size_t ob1 = ob0 + 1024;
#pragma unroll
    for (int m = 0; m < 4; ++m) {
      const int nn = 256 * m + t;
      float2 y = zb[l][PADi(4 * rt + m)];
      out[ob0 + nn] = feats[ob0 + nn] + y.x * s;
      out[ob1 + nn] = feats[ob1 + nn] + y.y * s;
    }
  }
}

// ---------------------------------------------------------------------------
extern "C" void kernel_launch(void* const* d_in, const int* in_sizes, int n_in,
                              void* d_out, int out_size, void* d_ws, size_t ws_size,
                              hipStream_t stream) {
  const float* feats  = (const float*)d_in[0];
  const float* lt1    = (const float*)d_in[1];
  const float* lt2    = (const float*)d_in[2];
  const float* w_t2f  = (const float*)d_in[3];
  const float* b_t2f  = (const float*)d_in[4];
  const float* w_df   = (const float*)d_in[5];
  const float* b_df   = (const float*)d_in[6];
  const float* w_t2f2 = (const float*)d_in[7];
  const float* b_t2f2 = (const float*)d_in[8];
  const float* w_df2  = (const float*)d_in[9];
  const float* b_df2  = (const float*)d_in[10];
  const float* scalep = (const float*)d_in[11];
  const int*   layerp = (const int*)d_in[12];
  float* out = (float*)d_out;
  (void)in_sizes; (void)n_in; (void)out_size; (void)ws_size;

  const size_t SZ = 8192ull * 1024ull;              // 8,388,608 elements
  short* Pa   = (short*)d_ws;                       // phase bf16 (16 MB)
  short* Pb   = Pa + SZ;                            // amp   bf16 (16 MB)
  short* awb  = Pb + SZ;                            // aw bf16, 2x8192x128 (4 MB)
  short* Tok  = awb + 2ull * 8192 * 128;            // tokens bf16, 4x128x1024 (1 MB)
  short* Wall = Tok + 4ull * 128 * 1024;            // weights bf16, 4x1024x1024 (8 MB)
  short* vrow = Wall + 4ull * 1024 * 1024;          // v row-major, 2x128x1024 (0.5 MB)
  short* V2T  = vrow + 2ull * 128 * 1024;           // w_df@v^T, 2x1024x128 (0.5 MB)
  short* dP   = V2T + 2ull * 1024 * 128;            // d_phase bf16 (16 MB)
  short* dA   = dP + SZ;                            // d_amp bf16 (16 MB)

  // 1: fwd fft2 + amp/phase (blocks 0..1023) + weight/token convert + cls copy
  fwd_fft2_amp_conv<<<dim3(5664), dim3(256), 0, stream>>>(
      feats, Pb, Pa, w_t2f, w_t2f2, w_df, w_df2, lt1, lt2, layerp,
      Wall, Tok, out);
  // 2: GEMM1+in+softmax (x<128, 64x128 tiles) and v-GEMM (x>=128), 512 thr
  gemm_sm_v<<<dim3(136, 1, 2), dim3(512), 0, stream>>>(
      Pa, Pb, Tok, Wall, b_t2f, b_t2f2, awb, vrow);
  // 3: V2T = w_df @ v^T  (M=1024, N=128, K=1024), bf16, ldc=128, dbuf pipeline
  gemm64<<<dim3(16, 1, 2), dim3(256), 0, stream>>>(
      Wall + 2 * 1024 * 1024, Wall + 3 * 1024 * 1024,
      vrow, vrow + 128 * 1024,
      V2T, V2T + 1024 * 128, 1024, 128);
  // 4: d = aw @ V2T^T + P @ w_df^T + b_df  (M=8192, N=1024, K=128+1024), bf16
  gemm256_dual<<<dim3(32, 4, 2), dim3(512), 0, stream>>>(
      awb, awb + 8192 * 128, V2T, V2T + 1024 * 128,
      Pa, Pb, Wall + 2 * 1024 * 1024, Wall + 3 * 1024 * 1024,
      b_df, b_df2, dP, dA, 128, 1024, 1024);
  // 5: fused inverse: polar -> ifft8 -> ifft_c -> residual (1 block/n)
  inv_fft2_res<<<dim3(1024), dim3(256), 0, stream>>>(dP, dA, feats, scalep, out);
}

// Round 16
// 240.656 us; speedup vs baseline: 1.0247x; 1.0101x over previous
//
#include <hip/hip_runtime.h>
#include <cstddef>

// ---------------------------------------------------------------------------
// Reins layer on MI355X — round 26.
// R25 = best (243.1; raw-rate rcp/sqrt won ~2.1us).  R26: instruction-count
// reduction in fwd's memory paths (same mechanism family — fwd is
// latency/issue-limited): (1) FFT staging re-spanned so each thread loads
// float4 pairs (32 scalar dword -> 8 dwordx4 per thread); (2) conv part
// packs 4 short stores into one short4.  Bit-identical values everywhere.
// All other kernels byte-identical to R25.
// Session ledger: gemm256_dual parked at 26-28% MfmaUtil across 5 schedule
// variants (unlock needs asm-level pipelining); FFTs latency-chain-bound.
// ---------------------------------------------------------------------------

using bf16x8 = __attribute__((ext_vector_type(8))) short;   // 8 bf16 in 4 VGPRs
using f32x4  = __attribute__((ext_vector_type(4))) float;

__device__ inline short f2bf(float f) {
  union { float f; unsigned u; } v; v.f = f;
  unsigned r = v.u + 0x7FFFu + ((v.u >> 16) & 1u);  // round-to-nearest-even
  return (short)(r >> 16);
}
__device__ inline float bf2f(short s) {
  union { unsigned u; float f; } v; v.u = ((unsigned)(unsigned short)s) << 16;
  return v.f;
}
__device__ inline void async16(const void* g, void* l) {
  __builtin_amdgcn_global_load_lds(
      (const __attribute__((address_space(1))) void*)g,
      (__attribute__((address_space(3))) void*)l, 16, 0, 0);
}
__device__ inline float fast_atan2(float y, float x) {   // max err ~1.5e-4 rad
  float ax = fabsf(x), ay = fabsf(y);
  float mx = fmaxf(ax, ay), mn = fminf(ax, ay);
  float a = mn * __builtin_amdgcn_rcpf(mx);              // raw v_rcp_f32 (1 ulp)
  float s = a * a;
  float r = fmaf(fmaf(fmaf(-0.0464964749f, s, 0.15931422f), s, -0.327622764f),
                 s * a, a);
  if (ay > ax) r = 1.5707963267948966f - r;
  if (x < 0.f) r = 3.14159265358979f - r;
  return (y < 0.f) ? -r : r;
}

__device__ inline int PADi(int i) { return i + (i >> 5); }   // LDS anti-conflict
__device__ inline int rev4_8(int t) {                         // reverse 4 base-4 digits
  return ((t & 3) << 6) | (((t >> 2) & 3) << 4) | (((t >> 4) & 3) << 2) | ((t >> 6) & 3);
}

// ---- radix-2 DIF FFT8, natural-order in & out ------------------------------
__device__ inline void fft8_fwd(float* xr, float* xi) {      // X[k]=Σx e^{-2πikb/8}
  const float r = 0.70710678118654752f;
  float ar[4], ai[4], br[4], bi[4], tr, ti;
  ar[0]=xr[0]+xr[4]; ai[0]=xi[0]+xi[4]; br[0]=xr[0]-xr[4]; bi[0]=xi[0]-xi[4];
  ar[1]=xr[1]+xr[5]; ai[1]=xi[1]+xi[5];
  tr=xr[1]-xr[5]; ti=xi[1]-xi[5]; br[1]=(tr+ti)*r; bi[1]=(ti-tr)*r;   // *(1-i)r
  ar[2]=xr[2]+xr[6]; ai[2]=xi[2]+xi[6];
  tr=xr[2]-xr[6]; ti=xi[2]-xi[6]; br[2]=ti; bi[2]=-tr;                // *(-i)
  ar[3]=xr[3]+xr[7]; ai[3]=xi[3]+xi[7];
  tr=xr[3]-xr[7]; ti=xi[3]-xi[7]; br[3]=(ti-tr)*r; bi[3]=-(tr+ti)*r;  // *-(1+i)r
  float u0r=ar[0]+ar[2], u0i=ai[0]+ai[2], u1r=ar[1]+ar[3], u1i=ai[1]+ai[3];
  float v0r=ar[0]-ar[2], v0i=ai[0]-ai[2];
  tr=ar[1]-ar[3]; ti=ai[1]-ai[3];
  float v1r=ti, v1i=-tr;                                              // *(-i)
  xr[0]=u0r+u1r; xi[0]=u0i+u1i; xr[4]=u0r-u1r; xi[4]=u0i-u1i;
  xr[2]=v0r+v1r; xi[2]=v0i+v1i; xr[6]=v0r-v1r; xi[6]=v0i-v1i;
  u0r=br[0]+br[2]; u0i=bi[0]+bi[2]; u1r=br[1]+br[3]; u1i=bi[1]+bi[3];
  v0r=br[0]-br[2]; v0i=bi[0]-bi[2];
  tr=br[1]-br[3]; ti=bi[1]-bi[3];
  v1r=ti; v1i=-tr;
  xr[1]=u0r+u1r; xi[1]=u0i+u1i; xr[5]=u0r-u1r; xi[5]=u0i-u1i;
  xr[3]=v0r+v1r; xi[3]=v0i+v1i; xr[7]=v0r-v1r; xi[7]=v0i-v1i;
}
__device__ inline void fft8_inv(float* xr, float* xi) {      // X[k]=Σx e^{+2πikb/8}
  const float r = 0.70710678118654752f;
  float ar[4], ai[4], br[4], bi[4], tr, ti;
  ar[0]=xr[0]+xr[4]; ai[0]=xi[0]+xi[4]; br[0]=xr[0]-xr[4]; bi[0]=xi[0]-xi[4];
  ar[1]=xr[1]+xr[5]; ai[1]=xi[1]+xi[5];
  tr=xr[1]-xr[5]; ti=xi[1]-xi[5]; br[1]=(tr-ti)*r; bi[1]=(tr+ti)*r;   // *(1+i)r
  ar[2]=xr[2]+xr[6]; ai[2]=xi[2]+xi[6];
  tr=xr[2]-xr[6]; ti=xi[2]-xi[6]; br[2]=-ti; bi[2]=tr;                // *(+i)
  ar[3]=xr[3]+xr[7]; ai[3]=xi[3]+xi[7];
  tr=xr[3]-xr[7]; ti=xi[3]-xi[7]; br[3]=-(tr+ti)*r; bi[3]=(tr-ti)*r;  // *(-1+i)r
  float u0r=ar[0]+ar[2], u0i=ai[0]+ai[2], u1r=ar[1]+ar[3], u1i=ai[1]+ai[3];
  float v0r=ar[0]-ar[2], v0i=ai[0]-ai[2];
  tr=ar[1]-ar[3]; ti=ai[1]-ai[3];
  float v1r=-ti, v1i=tr;                                              // *(+i)
  xr[0]=u0r+u1r; xi[0]=u0i+u1i; xr[4]=u0r-u1r; xi[4]=u0i-u1i;
  xr[2]=v0r+v1r; xi[2]=v0i+v1i; xr[6]=v0r-v1r; xi[6]=v0i-v1i;
  u0r=br[0]+br[2]; u0i=bi[0]+bi[2]; u1r=br[1]+br[3]; u1i=bi[1]+bi[3];
  v0r=br[0]-br[2]; v0i=bi[0]-bi[2];
  tr=br[1]-br[3]; ti=bi[1]-bi[3];
  v1r=-ti; v1i=tr;
  xr[1]=u0r+u1r; xi[1]=u0i+u1i; xr[5]=u0r-u1r; xi[5]=u0i-u1i;
  xr[3]=v0r+v1r; xi[3]=v0i+v1i; xr[7]=v0r-v1r; xi[7]=v0i-v1i;
}

// 1024-pt in-place radix-4 DIF, NP interleaved FFTs sharing barriers.
// Stage 0 mixes cross-wave -> block barrier.  Stages 1..4 are wave-local
// (wave w touches only elements 256w..256w+255) -> wave_barrier only.
// Final block barrier before cross-wave epilogue readers.
template <int SIGN, int NP>
__device__ inline void fft1024xN(float2 (*zb)[1056], int t) {
#pragma unroll
  for (int s = 0; s < 5; ++s) {
    const int Q = 256 >> (2 * s);
    const int j = t & (Q - 1);
    const int i0 = ((t & ~(Q - 1)) << 2) + j;
    const float ang = (float)SIGN * 6.283185307179586f * (float)j / (float)(4 * Q);
    float s1, c1; __sincosf(ang, &s1, &c1);
    const float c2 = c1 * c1 - s1 * s1, s2 = 2.f * c1 * s1;
    const float c3 = c2 * c1 - s2 * s1, s3 = c2 * s1 + s2 * c1;
#pragma unroll
    for (int p = 0; p < NP; ++p) {
      float2* z = zb[p];
      float2 x0 = z[PADi(i0)];
      float2 x1 = z[PADi(i0 + Q)];
      float2 x2 = z[PADi(i0 + 2 * Q)];
      float2 x3 = z[PADi(i0 + 3 * Q)];
      float t0x = x0.x + x2.x, t0y = x0.y + x2.y;
      float t1x = x0.x - x2.x, t1y = x0.y - x2.y;
      float t2x = x1.x + x3.x, t2y = x1.y + x3.y;
      float t3x = x1.x - x3.x, t3y = x1.y - x3.y;
      float u0x = t0x + t2x, u0y = t0y + t2y;
      float u2x = t0x - t2x, u2y = t0y - t2y;
      float u1x, u1y, u3x, u3y;
      if (SIGN < 0) { u1x = t1x + t3y; u1y = t1y - t3x; u3x = t1x - t3y; u3y = t1y + t3x; }
      else          { u1x = t1x - t3y; u1y = t1y + t3x; u3x = t1x + t3y; u3y = t1y - t3x; }
      z[PADi(i0)]         = make_float2(u0x, u0y);
      z[PADi(i0 + Q)]     = make_float2(u1x * c1 - u1y * s1, u1x * s1 + u1y * c1);
      z[PADi(i0 + 2 * Q)] = make_float2(u2x * c2 - u2y * s2, u2x * s2 + u2y * c2);
      z[PADi(i0 + 3 * Q)] = make_float2(u3x * c3 - u3y * s3, u3x * s3 + u3y * c3);
    }
    if (s == 0 || s == 4) __syncthreads();          // cross-wave boundaries only
    else                  __builtin_amdgcn_wave_barrier();  // compile-time order pin
  }
}

// ---- 1. fused fwd fft2 + amp/phase + conv work as extra blocks -------------
__global__ __launch_bounds__(256) void fwd_fft2_amp_conv(
    const float* __restrict__ feats,
    short* __restrict__ ampb, short* __restrict__ phaseb,
    const float* __restrict__ w1, const float* __restrict__ w2,
    const float* __restrict__ w3, const float* __restrict__ w4,
    const float* __restrict__ lt1, const float* __restrict__ lt2,
    const int* __restrict__ layerp,
    short* __restrict__ Wdst, short* __restrict__ Tdst,
    float* __restrict__ out) {
  if (blockIdx.x >= 1024) {                         // ---- conv part ----
    const int id = blockIdx.x - 1024;
    const int t4 = threadIdx.x * 4;
    if (id < 4096) {                                // weights: 4 x 1024 rows
      const int z = id >> 10, row = id & 1023;
      const float* W = (z == 0 ? w1 : z == 1 ? w2 : z == 2 ? w3 : w4)
                       + (size_t)row * 1024;
      short* D = Wdst + ((size_t)z * 1024 + row) * 1024;
      float4 v = *(const float4*)(W + t4);
      short4 sv; sv.x = f2bf(v.x); sv.y = f2bf(v.y); sv.z = f2bf(v.z); sv.w = f2bf(v.w);
      *(short4*)(D + t4) = sv;                      // packed 8B store
    } else if (id < 4608) {                         // tokens: 4 x 128 rows
      const int i2 = id - 4096;
      const int zz = i2 >> 7, row = i2 & 127;
      const int z = zz & 1, shift = zz >> 1;
      short* D = Tdst + ((size_t)zz * 128 + row) * 1024;
      if (row + shift < 100) {
        const float* S = (z ? lt2 : lt1) + (size_t)layerp[0] * 102400
                         + (size_t)(row + shift) * 1024;
        float4 v = *(const float4*)(S + t4);
        short4 sv; sv.x = f2bf(v.x); sv.y = f2bf(v.y); sv.z = f2bf(v.z); sv.w = f2bf(v.w);
        *(short4*)(D + t4) = sv;
      } else {
        *(short4*)(D + t4) = make_short4(0, 0, 0, 0);
      }
    } else {                                        // cls: 32 blocks x 256
      const int i = (id - 4608) * 256 + threadIdx.x;
      out[i] = feats[i];
    }
    return;
  }
  // ---- FFT part ----
  __shared__ float2 zb[4][1056];                    // 33.8 KB
  const int t = threadIdx.x;
  const int n = blockIdx.x;
  const float* base = feats + 8192 + (size_t)n * 8192;
  // R26: vectorized staging — thread t owns columns 4t..4t+3 (float4 loads)
  const int c4 = t * 4;
#pragma unroll
  for (int p = 0; p < 4; ++p) {
    const float* x0 = base + (size_t)(2 * p) * 1024;
    const float* x1 = x0 + 1024;
    float4 a = *(const float4*)(x0 + c4);
    float4 b = *(const float4*)(x1 + c4);
    zb[p][PADi(c4 + 0)] = make_float2(a.x, b.x);
    zb[p][PADi(c4 + 1)] = make_float2(a.y, b.y);
    zb[p][PADi(c4 + 2)] = make_float2(a.z, b.z);
    zb[p][PADi(c4 + 3)] = make_float2(a.w, b.w);
  }
  __syncthreads();
  fft1024xN<-1, 4>(zb, t);
  const int rt = rev4_8(t);
  short* ab = ampb + (size_t)n * 8192;
  short* pb = phaseb + (size_t)n * 8192;
#pragma unroll
  for (int m = 0; m < 4; ++m) {
    const int k = 256 * m + t;
    const int kk = (1024 - k) & 1023;
    const int pos  = 4 * rt + m;
    const int pos2 = 4 * rev4_8(kk & 255) + (kk >> 8);
    float xr[8], xi[8];
#pragma unroll
    for (int p = 0; p < 4; ++p) {
      float2 Z = zb[p][PADi(pos)];
      float2 W = zb[p][PADi(pos2)];
      xr[2 * p]     = 0.5f * (Z.x + W.x);
      xi[2 * p]     = 0.5f * (Z.y - W.y);
      xr[2 * p + 1] = 0.5f * (Z.y + W.y);
      xi[2 * p + 1] = 0.5f * (W.x - Z.x);
    }
    fft8_fwd(xr, xi);                               // X[kb] along batch dim
#pragma unroll
    for (int kb = 0; kb < 8; ++kb) {
      float sr = xr[kb], si = xi[kb];
      float r2 = sr * sr + si * si;
      if (r2 < 1e-5f) r2 = 1e-5f;                   // _replace_denormals(re^2+im^2)
      float a = __builtin_amdgcn_sqrtf(r2);         // raw v_sqrt_f32 (1 ulp)
      float rr = (sr < 1e-5f && sr > -1e-5f) ? 1e-5f : sr;
      float ph = fast_atan2(si, rr);
      ab[kb * 1024 + k] = f2bf(a);
      pb[kb * 1024 + k] = f2bf(ph);
    }
  }
}

// ---- 2. GEMM1+softmax (x<128, 64x128 tile) and v-GEMM (x>=128), one grid ---
// 512 threads (8 waves).  Softmax part: per-wave 32x32 sub-tile; staging by
// tid<256 only; softmax 8 lanes/row.  v-GEMM: per-wave 64x32, 2 async16/thr.
__global__ __launch_bounds__(512) void gemm_sm_v(
    const short* A0, const short* A1,       // 8192 x 1024 bf16 (phase, amp)
    const short* Tok,                       // 4 x 128 x 1024 bf16 tokens
    const short* Wall,                      // 4 x 1024 x 1024 bf16 weights
    const float* bt1, const float* bt2,     // b_t2f, b_t2f2
    short* __restrict__ awb,                // 2 x 8192 x 128 bf16
    short* __restrict__ vrow) {             // 2 x 128 x 1024 bf16
  __shared__ __align__(16) char smem[37120];
  const int z = blockIdx.z;
  const int tid = threadIdx.x;
  const int wave = tid >> 6, lane = tid & 63;
  const int m16 = lane & 15, quad = lane >> 4;
  const int fcol = ((quad ^ ((m16 >> 1) & 3)) * 8) + m16 * 32;

  if (blockIdx.x >= 128) {                          // ---- v-GEMM part (BK=32) --
    const int jbBlk = blockIdx.x - 128;             // column block 0..7
    const short* A = Tok + (size_t)(2 + z) * 128 * 1024;   // shifted tokens
    const short* B = Wall + (size_t)z * 1024 * 1024;       // w_t2f / w_t2f2
    const float* bias = z ? bt2 : bt1;
    short* C = vrow + (size_t)z * 128 * 1024;
    const int K = 1024;
    short* As = (short*)smem;                       // 128 x 32
    short* Bs = (short*)(smem + 8192);              // 128 x 32
    const int wm = (wave & 1) * 64, wn = (wave >> 1) * 32;
    f32x4 acc[4][2];
#pragma unroll
    for (int i = 0; i < 4; ++i)
#pragma unroll
      for (int j = 0; j < 2; ++j) acc[i][j] = (f32x4){0.f, 0.f, 0.f, 0.f};
    const int r0v = tid >> 2;                       // 0..127
    const int cswv = (((tid & 3) ^ ((r0v >> 1) & 3)) * 8);
    const short* aSrc = A + (size_t)r0v * K + cswv;
    const short* bSrc = B + (size_t)(jbBlk * 128 + r0v) * K + cswv;
    short* aDst = As + tid * 8;
    short* bDst = Bs + tid * 8;
    for (int k0 = 0; k0 < K; k0 += 32) {
      async16(aSrc + k0, aDst);
      async16(bSrc + k0, bDst);
      __syncthreads();
      bf16x8 af[4], bg[2];
#pragma unroll
      for (int ib = 0; ib < 4; ++ib)
        af[ib] = *(const bf16x8*)(As + (wm + ib * 16) * 32 + fcol);
#pragma unroll
      for (int jb2 = 0; jb2 < 2; ++jb2)
        bg[jb2] = *(const bf16x8*)(Bs + (wn + jb2 * 16) * 32 + fcol);
#pragma unroll
      for (int ib = 0; ib < 4; ++ib)
#pragma unroll
        for (int jb2 = 0; jb2 < 2; ++jb2)
          acc[ib][jb2] = __builtin_amdgcn_mfma_f32_16x16x32_bf16(af[ib], bg[jb2], acc[ib][jb2], 0, 0, 0);
      __syncthreads();
    }
#pragma unroll
    for (int ib = 0; ib < 4; ++ib) {
      const int rowb = wm + ib * 16 + quad * 4;
#pragma unroll
      for (int jb2 = 0; jb2 < 2; ++jb2) {
        const int col = jbBlk * 128 + wn + jb2 * 16 + m16;
        const float bcv = bias[col];
#pragma unroll
        for (int r = 0; r < 4; ++r)
          C[(size_t)(rowb + r) * 1024 + col] = f2bf(acc[ib][jb2][r] + bcv);
      }
    }
    return;
  }

  // ---- softmax-GEMM part, 64x128 tile, BK=64, 8 waves ----
  const short* A = z ? A1 : A0;
  const short* B = Tok + (size_t)z * 128 * 1024;
  const int K = 1024;
  short* As = (short*)smem;                         // [2][64*32]  (8 KB)   K-loop only
  short* Bs = (short*)(smem + 8192);                // [2][128*32] (16 KB)  K-loop only
  float (*ltile)[129] = (float(*)[129])(smem);      // 64x129 f32 (33 KB)  post-loop overlay
  float (*red1)[8] = (float(*)[8])(smem + 33024);   // 64x8 (2 KB)
  float (*red2)[8] = (float(*)[8])(smem + 35072);   // 64x8 (2 KB)
  const int wm = (wave & 1) * 32, wn = (wave >> 1) * 32;
  f32x4 acc[2][2];
#pragma unroll
  for (int i = 0; i < 2; ++i)
#pragma unroll
    for (int j = 0; j < 2; ++j) acc[i][j] = (f32x4){0.f, 0.f, 0.f, 0.f};
  // staging by tid<256 only — identical address pattern to R20
  const int r0s = (tid & 255) >> 2;
  const int csws = (((tid & 3) ^ ((r0s >> 1) & 3)) * 8);
  const short* aSrc  = A + (size_t)(blockIdx.x * 64 + r0s) * K + csws;
  const short* bSrc0 = B + (size_t)r0s * K + csws;
  const short* bSrc1 = bSrc0 + (size_t)64 * K;
  short* aDst0  = As + (tid & 255) * 8;             // sub0: 64x32
  short* aDst1  = As + 2048 + (tid & 255) * 8;      // sub1
  short* bDst00 = Bs + (tid & 255) * 8;             // sub0 rows 0-63
  short* bDst01 = Bs + 2048 + (tid & 255) * 8;      // sub0 rows 64-127
  short* bDst10 = Bs + 4096 + (tid & 255) * 8;      // sub1 rows 0-63
  short* bDst11 = Bs + 6144 + (tid & 255) * 8;      // sub1 rows 64-127
  for (int k0 = 0; k0 < K; k0 += 64) {
    if (tid < 256) {
      async16(aSrc + k0,       aDst0);
      async16(aSrc + k0 + 32,  aDst1);
      async16(bSrc0 + k0,      bDst00);
      async16(bSrc1 + k0,      bDst01);
      async16(bSrc0 + k0 + 32, bDst10);
      async16(bSrc1 + k0 + 32, bDst11);
    }
    __syncthreads();
#pragma unroll
    for (int sub = 0; sub < 2; ++sub) {
      bf16x8 af[2], bg[2];
#pragma unroll
      for (int ib = 0; ib < 2; ++ib)
        af[ib] = *(const bf16x8*)(As + sub * 2048 + (wm + ib * 16) * 32 + fcol);
#pragma unroll
      for (int jb = 0; jb < 2; ++jb)
        bg[jb] = *(const bf16x8*)(Bs + sub * 4096 + (wn + jb * 16) * 32 + fcol);
#pragma unroll
      for (int ib = 0; ib < 2; ++ib)
#pragma unroll
        for (int jb = 0; jb < 2; ++jb)
          acc[ib][jb] = __builtin_amdgcn_mfma_f32_16x16x32_bf16(af[ib], bg[jb], acc[ib][jb], 0, 0, 0);
    }
    __syncthreads();
  }
  // staging region dead; ltile overlays it (ordered by barrier above)
#pragma unroll
  for (int ib = 0; ib < 2; ++ib)
#pragma unroll
    for (int jb = 0; jb < 2; ++jb)
#pragma unroll
      for (int r = 0; r < 4; ++r)
        ltile[wm + ib * 16 + quad * 4 + r][wn + jb * 16 + m16] = acc[ib][jb][r];
  __syncthreads();
  const int row = tid >> 3, l8 = tid & 7;           // 8 lanes/row, 64 rows
  float s = 0.f, q = 0.f;
  for (int c = l8; c < 100; c += 8) { float x = ltile[row][c]; s += x; q += x * x; }
  red1[row][l8] = s; red2[row][l8] = q;
  __syncthreads();
  float ssum = 0.f, qsum = 0.f;
#pragma unroll
  for (int i = 0; i < 8; ++i) { ssum += red1[row][i]; qsum += red2[row][i]; }
  __syncthreads();
  const float mu = ssum * 0.01f;
  const float rinv = rsqrtf(fmaxf(qsum * 0.01f - mu * mu, 0.f) + 1e-5f);
  float mx = -3.4e38f;
  for (int c = l8; c < 100; c += 8) {
    float x = ltile[row][c];
    if (z == 1) x = (x - mu) * rinv;                // instance-norm (amp path)
    x *= 0.03125f;                                  // * C^{-1/2}
    ltile[row][c] = x;
    mx = fmaxf(mx, x);
  }
  red1[row][l8] = mx;
  __syncthreads();
#pragma unroll
  for (int i = 0; i < 8; ++i) mx = fmaxf(mx, red1[row][i]);
  __syncthreads();
  float es = 0.f;
  for (int c = l8; c < 100; c += 8) {
    float e = __expf(ltile[row][c] - mx);
    ltile[row][c] = e; es += e;
  }
  red1[row][l8] = es;
  __syncthreads();
  float tot = 0.f;
#pragma unroll
  for (int i = 0; i < 8; ++i) tot += red1[row][i];
  const float inv = 1.f / tot;
  short* Aout = awb + ((size_t)z * 8192 + (size_t)blockIdx.x * 64 + row) * 128;
  for (int c = l8; c < 100; c += 8)
    if (c >= 1) Aout[c - 1] = f2bf(ltile[row][c] * inv);  // aw[k]=attn[k+1]
  for (int k = l8; k < 128; k += 8)
    if (k >= 99) Aout[k] = 0;                             // zero pad 99..127
}

// ------------- 64x128-tile GEMM (V2T), double-buffered ----------------------
__global__ __launch_bounds__(256) void gemm64(
    const short* A0, const short* A1,       // M x K bf16
    const short* B0, const short* B1,       // 128 x K bf16
    void* C0v, void* C1v, int K, int ldc) {
  const int z = blockIdx.z;
  const short* A = z ? A1 : A0;
  const short* B = z ? B1 : B0;
  void* Cv = z ? C1v : C0v;
  __shared__ __align__(16) short As[2][64 * 32];    // 8 KB
  __shared__ __align__(16) short Bs[2][128 * 32];   // 16 KB
  const int tid = threadIdx.x;
  const int wave = tid >> 6, lane = tid & 63;
  const int m16 = lane & 15, quad = lane >> 4;
  const int wm = (wave & 1) * 32, wn = (wave >> 1) * 64;
  f32x4 acc[2][4];
#pragma unroll
  for (int i = 0; i < 2; ++i)
#pragma unroll
    for (int j = 0; j < 4; ++j) acc[i][j] = (f32x4){0.f, 0.f, 0.f, 0.f};
  const int r0 = tid >> 2;
  const int csw = (((tid & 3) ^ ((r0 >> 1) & 3)) * 8);
  const short* aSrc  = A + (size_t)(blockIdx.x * 64 + r0) * K + csw;
  const short* bSrc0 = B + (size_t)r0 * K + csw;
  const short* bSrc1 = bSrc0 + (size_t)64 * K;
  const int fcol = ((quad ^ ((m16 >> 1) & 3)) * 8) + m16 * 32;
  const int NIT = K >> 5;                           // 32
  // prologue: stage buffer 0 (k0 = 0)
  async16(aSrc,  As[0] + tid * 8);
  async16(bSrc0, Bs[0] + tid * 8);
  async16(bSrc1, Bs[0] + 2048 + tid * 8);
#pragma unroll 1
  for (int it = 0; it < NIT; ++it) {
    const int cur = it & 1;
    if (it + 1 < NIT) {                             // stage next buffer
      const int k0n = (it + 1) << 5;
      async16(aSrc + k0n,  As[cur ^ 1] + tid * 8);
      async16(bSrc0 + k0n, Bs[cur ^ 1] + tid * 8);
      async16(bSrc1 + k0n, Bs[cur ^ 1] + 2048 + tid * 8);
      asm volatile("s_waitcnt vmcnt(3)" ::: "memory");   // oldest 3 = cur's loads
    } else {
      asm volatile("s_waitcnt vmcnt(0)" ::: "memory");
    }
    __builtin_amdgcn_sched_barrier(0);
    __builtin_amdgcn_s_barrier();
    bf16x8 af[2], bg[4];
#pragma unroll
    for (int ib = 0; ib < 2; ++ib)
      af[ib] = *(const bf16x8*)(&As[cur][0] + (wm + ib * 16) * 32 + fcol);
#pragma unroll
    for (int jb = 0; jb < 4; ++jb)
      bg[jb] = *(const bf16x8*)(&Bs[cur][0] + (wn + jb * 16) * 32 + fcol);
#pragma unroll
    for (int ib = 0; ib < 2; ++ib)
#pragma unroll
      for (int jb = 0; jb < 4; ++jb)
        acc[ib][jb] = __builtin_amdgcn_mfma_f32_16x16x32_bf16(af[ib], bg[jb], acc[ib][jb], 0, 0, 0);
    __builtin_amdgcn_sched_barrier(0);
    __builtin_amdgcn_s_barrier();
  }
#pragma unroll
  for (int ib = 0; ib < 2; ++ib) {
    const int rowb = blockIdx.x * 64 + wm + ib * 16 + quad * 4;
#pragma unroll
    for (int jb = 0; jb < 4; ++jb) {
      const int col = wn + jb * 16 + m16;
#pragma unroll
      for (int r = 0; r < 4; ++r)
        ((short*)Cv)[(size_t)(rowb + r) * ldc + col] = f2bf(acc[ib][jb][r]);
    }
  }
}

// ---- dual-K fused GEMM, 256x256 tile, 8-phase schedule (T3+T4+T5) ----------
#define SLOT8(VM, DOSTAGE)                                                   \
  do {                                                                       \
    const short* Asl = &As[k & 3][0];                                        \
    const short* Bsl = &Bs[k & 3][0];                                        \
    const int kp = k + 3;                                                    \
    const short *as0 = nullptr, *as1 = nullptr, *bs0 = nullptr, *bs1 = nullptr; \
    short *ad = nullptr, *bd = nullptr;                                      \
    if (DOSTAGE) {                                                           \
      ad = &As[kp & 3][0]; bd = &Bs[kp & 3][0];                              \
      if (kp < NS1) {                                                        \
        const int c = kp << 5;                                               \
        as0 = A1 + aO1_0 + c; as1 = A1 + aO1_1 + c;                          \
        bs0 = B1 + bO1_0 + c; bs1 = B1 + bO1_1 + c;                          \
      } else {                                                               \
        const int c = (kp - NS1) << 5;                                       \
        as0 = A2 + aO2_0 + c; as1 = A2 + aO2_1 + c;                          \
        bs0 = B2 + bO2_0 + c; bs1 = B2 + bO2_1 + c;                          \
      }                                                                      \
    }                                                                        \
    bf16x8 bg[4], af[4];                                                     \
    /* ---- phase A: bg + af(rows wm..wm+63) + stage A-half of k+3 ---- */   \
    _Pragma("unroll")                                                        \
    for (int jb = 0; jb < 4; ++jb)                                           \
      bg[jb] = *(const bf16x8*)(Bsl + (wn + jb * 16) * 32 + fcol);           \
    _Pragma("unroll")                                                        \
    for (int ib = 0; ib < 4; ++ib)                                           \
      af[ib] = *(const bf16x8*)(Asl + (wm + ib * 16) * 32 + fcol);           \
    if (DOSTAGE) {                                                           \
      async16(as0, ad + tid * 8);                                            \
      async16(as1, ad + 4096 + tid * 8);                                     \
    }                                                                        \
    __builtin_amdgcn_sched_barrier(0);                                       \
    __builtin_amdgcn_s_barrier();                                            \
    asm volatile("s_waitcnt lgkmcnt(0)" ::: "memory");                       \
    __builtin_amdgcn_s_setprio(1);                                           \
    _Pragma("unroll")                                                        \
    for (int ib = 0; ib < 4; ++ib)                                           \
      _Pragma("unroll")                                                      \
      for (int jb = 0; jb < 4; ++jb)                                         \
        acc[ib][jb] = __builtin_amdgcn_mfma_f32_16x16x32_bf16(               \
            af[ib], bg[jb], acc[ib][jb], 0, 0, 0);                           \
    __builtin_amdgcn_s_setprio(0);                                           \
    __builtin_amdgcn_sched_barrier(0);                                       \
    __builtin_amdgcn_s_barrier();                                            \
    /* ---- phase B: af(rows wm+64..wm+127) + stage B-half of k+3 ---- */    \
    _Pragma("unroll")                                                        \
    for (int ib = 0; ib < 4; ++ib)                                           \
      af[ib] = *(const bf16x8*)(Asl + (wm + 64 + ib * 16) * 32 + fcol);      \
    if (DOSTAGE) {                                                           \
      async16(bs0, bd + tid * 8);                                            \
      async16(bs1, bd + 4096 + tid * 8);                                     \
    }                                                                        \
    __builtin_amdgcn_sched_barrier(0);                                       \
    __builtin_amdgcn_s_barrier();                                            \
    asm volatile("s_waitcnt lgkmcnt(0)" ::: "memory");                       \
    __builtin_amdgcn_s_setprio(1);                                           \
    _Pragma("unroll")                                                        \
    for (int ib = 0; ib < 4; ++ib)                                           \
      _Pragma("unroll")                                                      \
      for (int jb = 0; jb < 4; ++jb)                                         \
        acc[ib + 4][jb] = __builtin_amdgcn_mfma_f32_16x16x32_bf16(           \
            af[ib], bg[jb], acc[ib + 4][jb], 0, 0, 0);                       \
    __builtin_amdgcn_s_setprio(0);                                           \
    asm volatile("s_waitcnt vmcnt(" #VM ")" ::: "memory");                   \
    __builtin_amdgcn_sched_barrier(0);                                       \
    __builtin_amdgcn_s_barrier();                                            \
  } while (0)

__global__ __launch_bounds__(512) void gemm256_dual(
    const short* A1_0, const short* A1_1,   // M x K1
    const short* B1_0, const short* B1_1,   // N x K1
    const short* A2_0, const short* A2_1,   // M x K2
    const short* B2_0, const short* B2_1,   // N x K2
    const float* bias0, const float* bias1,
    short* C0, short* C1, int K1, int K2, int ldc) {
  const int z = blockIdx.z;
  const short* A1 = z ? A1_1 : A1_0;
  const short* B1 = z ? B1_1 : B1_0;
  const short* A2 = z ? A2_1 : A2_0;
  const short* B2 = z ? B2_1 : B2_0;
  const float* bias = z ? bias1 : bias0;
  short* C = z ? C1 : C0;
  __shared__ __align__(16) short As[4][8192];       // 4 slots x 256x32 (64 KB)
  __shared__ __align__(16) short Bs[4][8192];       // 4 slots x 256x32 (64 KB)
  const int tid = threadIdx.x;
  const int wave = tid >> 6, lane = tid & 63;
  const int m16 = lane & 15, quad = lane >> 4;
  const int wm = (wave & 1) * 128, wn = (wave >> 1) * 64;
  const int fcol = ((quad ^ ((m16 >> 1) & 3)) * 8) + m16 * 32;
  const int r0 = tid >> 2;                          // 0..127
  const int csw = (((tid & 3) ^ ((r0 >> 1) & 3)) * 8);
  const size_t aO1_0 = (size_t)(blockIdx.x * 256 + r0) * (size_t)K1 + csw;
  const size_t aO1_1 = aO1_0 + (size_t)128 * K1;
  const size_t bO1_0 = (size_t)(blockIdx.y * 256 + r0) * (size_t)K1 + csw;
  const size_t bO1_1 = bO1_0 + (size_t)128 * K1;
  const size_t aO2_0 = (size_t)(blockIdx.x * 256 + r0) * (size_t)K2 + csw;
  const size_t aO2_1 = aO2_0 + (size_t)128 * K2;
  const size_t bO2_0 = (size_t)(blockIdx.y * 256 + r0) * (size_t)K2 + csw;
  const size_t bO2_1 = bO2_0 + (size_t)128 * K2;
  const int NS1 = K1 >> 5;                          // 4
  const int NT  = NS1 + (K2 >> 5);                  // 36
  f32x4 acc[8][4];
#pragma unroll
  for (int i = 0; i < 8; ++i)
#pragma unroll
    for (int j = 0; j < 4; ++j) acc[i][j] = (f32x4){0.f, 0.f, 0.f, 0.f};
  // prologue: stage slots 0..2 fully (12 loads in flight per wave)
#pragma unroll
  for (int k = 0; k < 3; ++k) {
    short* ad = &As[k & 3][0];
    short* bd = &Bs[k & 3][0];
    const short *as0, *as1, *bs0, *bs1;
    if (k < NS1) {
      const int c = k << 5;
      as0 = A1 + aO1_0 + c; as1 = A1 + aO1_1 + c;
      bs0 = B1 + bO1_0 + c; bs1 = B1 + bO1_1 + c;
    } else {
      const int c = (k - NS1) << 5;
      as0 = A2 + aO2_0 + c; as1 = A2 + aO2_1 + c;
      bs0 = B2 + bO2_0 + c; bs1 = B2 + bO2_1 + c;
    }
    async16(as0, ad + tid * 8);
    async16(as1, ad + 4096 + tid * 8);
    async16(bs0, bd + tid * 8);
    async16(bs1, bd + 4096 + tid * 8);
  }
  // gate slot 0: oldest 4 of 12 loads must land
  asm volatile("s_waitcnt vmcnt(8)" ::: "memory");
  __builtin_amdgcn_sched_barrier(0);
  __builtin_amdgcn_s_barrier();
#pragma unroll 1
  for (int k = 0; k < NT - 3; ++k) {                // k = 0..32, always stages
    SLOT8(8, true);
  }
  { const int k = NT - 3; SLOT8(4, false); }        // gate slot NT-2
  { const int k = NT - 2; SLOT8(0, false); }        // gate slot NT-1
  { const int k = NT - 1; SLOT8(0, false); }        // last slot
  // epilogue
#pragma unroll
  for (int ib = 0; ib < 8; ++ib) {
    const int rowb = blockIdx.x * 256 + wm + ib * 16 + quad * 4;
#pragma unroll
    for (int jb = 0; jb < 4; ++jb) {
      const int col = blockIdx.y * 256 + wn + jb * 16 + m16;
      const float bcv = bias[col];
#pragma unroll
      for (int r = 0; r < 4; ++r) {
        const size_t idx = (size_t)(rowb + r) * (size_t)ldc + col;
        C[idx] = f2bf(acc[ib][jb][r] + bcv);
      }
    }
  }
}
#undef SLOT8

// ---- fused inverse: polar->z, FFT8 inv, Hermitian-packed ifft, residual ----
__global__ __launch_bounds__(256) void inv_fft2_res(const short* __restrict__ dPb,
                                                    const short* __restrict__ dAb,
                                                    const float* __restrict__ feats,
                                                    const float* __restrict__ scalep,
                                                    float* __restrict__ out) {
  __shared__ float2 zb[4][1056];                    // 33.8 KB -> 4 blocks/CU
  const int t = threadIdx.x;
  const int n = blockIdx.x;
  const short* pp = dPb + (size_t)n * 8192;
  const short* ap = dAb + (size_t)n * 8192;
  const float invs = 0.022097086912079608f;         // 1/sqrt(2048)
  const float inv8 = 0.35355339059327373f;          // 1/sqrt(8) (ortho)
  for (int k = t; k < 513; k += 256) {
    float zr[8], zi[8];
#pragma unroll
    for (int b = 0; b < 8; ++b) {
      float p = bf2f(pp[b * 1024 + k]);
      float a = bf2f(ap[b * 1024 + k]) * invs;
      float s, c; __sincosf(p, &s, &c);
      zr[b] = c * a; zi[b] = s * a;
    }
    fft8_inv(zr, zi);                               // Z[bp] = ifft along batch
#pragma unroll
    for (int l = 0; l < 4; ++l) {
      const int bp = 2 * l;                         // pair (bp, bp+1)
      float ax = zr[bp] * inv8,     ay = zi[bp] * inv8;
      float bx = zr[bp + 1] * inv8, by = zi[bp + 1] * inv8;
      zb[l][PADi(k)] = make_float2(ax - by, ay + bx);   // Y = Za + i*Zb
      if (k >= 1 && k <= 511)
        zb[l][PADi(1024 - k)] = make_float2(ax + by, bx - ay);
    }
  }
  __syncthreads();
  fft1024xN<1, 4>(zb, t);
  const int rt = rev4_8(t);
  const float s = scalep[0] * 0.03125f;             // scale * 1/sqrt(1024)
#pragma unroll
  for (int l = 0; l < 4; ++l) {
    const size_t ob0 = 8192 + ((size_t)n * 8 + 2 * l) * 1024;
    const size_t ob1 = ob0 + 1024;
#pragma unroll
    for (int m = 0; m < 4; ++m) {
      const int nn = 256 * m + t;
      float2 y = zb[l][PADi(4 * rt + m)];
      out[ob0 + nn] = feats[ob0 + nn] + y.x * s;
      out[ob1 + nn] = feats[ob1 + nn] + y.y * s;
    }
  }
}

// ---------------------------------------------------------------------------
extern "C" void kernel_launch(void* const* d_in, const int* in_sizes, int n_in,
                              void* d_out, int out_size, void* d_ws, size_t ws_size,
                              hipStream_t stream) {
  const float* feats  = (const float*)d_in[0];
  const float* lt1    = (const float*)d_in[1];
  const float* lt2    = (const float*)d_in[2];
  const float* w_t2f  = (const float*)d_in[3];
  const float* b_t2f  = (const float*)d_in[4];
  const float* w_df   = (const float*)d_in[5];
  const float* b_df   = (const float*)d_in[6];
  const float* w_t2f2 = (const float*)d_in[7];
  const float* b_t2f2 = (const float*)d_in[8];
  const float* w_df2  = (const float*)d_in[9];
  const float* b_df2  = (const float*)d_in[10];
  const float* scalep = (const float*)d_in[11];
  const int*   layerp = (const int*)d_in[12];
  float* out = (float*)d_out;
  (void)in_sizes; (void)n_in; (void)out_size; (void)ws_size;

  const size_t SZ = 8192ull * 1024ull;              // 8,388,608 elements
  short* Pa   = (short*)d_ws;                       // phase bf16 (16 MB)
  short* Pb   = Pa + SZ;                            // amp   bf16 (16 MB)
  short* awb  = Pb + SZ;                            // aw bf16, 2x8192x128 (4 MB)
  short* Tok  = awb + 2ull * 8192 * 128;            // tokens bf16, 4x128x1024 (1 MB)
  short* Wall = Tok + 4ull * 128 * 1024;            // weights bf16, 4x1024x1024 (8 MB)
  short* vrow = Wall + 4ull * 1024 * 1024;          // v row-major, 2x128x1024 (0.5 MB)
  short* V2T  = vrow + 2ull * 128 * 1024;           // w_df@v^T, 2x1024x128 (0.5 MB)
  short* dP   = V2T + 2ull * 1024 * 128;            // d_phase bf16 (16 MB)
  short* dA   = dP + SZ;                            // d_amp bf16 (16 MB)

  // 1: fwd fft2 + amp/phase (blocks 0..1023) + weight/token convert + cls copy
  fwd_fft2_amp_conv<<<dim3(5664), dim3(256), 0, stream>>>(
      feats, Pb, Pa, w_t2f, w_t2f2, w_df, w_df2, lt1, lt2, layerp,
      Wall, Tok, out);
  // 2: GEMM1+in+softmax (x<128, 64x128 tiles) and v-GEMM (x>=128), 512 thr
  gemm_sm_v<<<dim3(136, 1, 2), dim3(512), 0, stream>>>(
      Pa, Pb, Tok, Wall, b_t2f, b_t2f2, awb, vrow);
  // 3: V2T = w_df @ v^T  (M=1024, N=128, K=1024), bf16, ldc=128, dbuf pipeline
  gemm64<<<dim3(16, 1, 2), dim3(256), 0, stream>>>(
      Wall + 2 * 1024 * 1024, Wall + 3 * 1024 * 1024,
      vrow, vrow + 128 * 1024,
      V2T, V2T + 1024 * 128, 1024, 128);
  // 4: d = aw @ V2T^T + P @ w_df^T + b_df  (M=8192, N=1024, K=128+1024), bf16
  gemm256_dual<<<dim3(32, 4, 2), dim3(512), 0, stream>>>(
      awb, awb + 8192 * 128, V2T, V2T + 1024 * 128,
      Pa, Pb, Wall + 2 * 1024 * 1024, Wall + 3 * 1024 * 1024,
      b_df, b_df2, dP, dA, 128, 1024, 1024);
  // 5: fused inverse: polar -> ifft8 -> ifft_c -> residual (1 block/n)
  inv_fft2_res<<<dim3(1024), dim3(256), 0, stream>>>(dP, dA, feats, scalep, out);
}